// Round 1
// baseline (1733.603 us; speedup 1.0000x reference)
//
#include <hip/hip_runtime.h>
#include <math.h>

#define N_REL 16
#define D_E 64
#define D_OUT 32

// ---------------------------------------------------------------------------
// Stage 1: histogram of in-degrees
__global__ __launch_bounds__(256) void hist_kernel(const int* __restrict__ dst,
                                                   int* __restrict__ counts, int E) {
    int i = blockIdx.x * blockDim.x + threadIdx.x;
    if (i < E) atomicAdd(&counts[dst[i]], 1);
}

// ---------------------------------------------------------------------------
// Stage 2: single-block exclusive scan over counts -> offsets (+cursor copy)
__global__ __launch_bounds__(1024) void scan_kernel(const int* __restrict__ counts,
                                                    int* __restrict__ offsets,
                                                    int* __restrict__ cursor, int n) {
    __shared__ int lds[1024];
    int t = threadIdx.x;
    int C = (n + 1023) >> 10;           // chunk per thread
    int base = t * C;
    int end = min(base + C, n);
    int s = 0;
    for (int i = base; i < end; ++i) s += counts[i];
    lds[t] = s;
    __syncthreads();
    // Hillis-Steele inclusive scan
    for (int off = 1; off < 1024; off <<= 1) {
        int v = (t >= off) ? lds[t - off] : 0;
        __syncthreads();
        lds[t] += v;
        __syncthreads();
    }
    int run = (t == 0) ? 0 : lds[t - 1];
    for (int i = base; i < end; ++i) {
        offsets[i] = run;
        cursor[i] = run;
        run += counts[i];
    }
    if (t == 1023) offsets[n] = lds[1023];
}

// ---------------------------------------------------------------------------
// Stage 3: scatter edge ids into CSR buckets
__global__ __launch_bounds__(256) void scatter_kernel(const int* __restrict__ dst,
                                                      int* __restrict__ cursor,
                                                      int* __restrict__ eids, int E) {
    int i = blockIdx.x * blockDim.x + threadIdx.x;
    if (i < E) {
        int pos = atomicAdd(&cursor[dst[i]], 1);
        eids[pos] = i;
    }
}

// ---------------------------------------------------------------------------
// Stage 4: per-edge attention logit. One wave (64 lanes) per edge.
// att[e] = sum_j (h W_r)[j] * tanh((t W_r)[j] + rel[r][j])
__global__ __launch_bounds__(256) void att_kernel(const float* __restrict__ ent,
                                                  const float* __restrict__ rel,
                                                  const float* __restrict__ WR,
                                                  const int* __restrict__ src,
                                                  const int* __restrict__ dst,
                                                  const int* __restrict__ etype,
                                                  float* __restrict__ att, int E) {
    int wid = (blockIdx.x * blockDim.x + threadIdx.x) >> 6;  // edge id
    int lane = threadIdx.x & 63;
    if (wid >= E) return;
    int s = src[wid];
    int d = dst[wid];
    int r = etype[wid];
    float h = ent[s * D_E + lane];
    float t = ent[d * D_E + lane];
    float rv = rel[r * D_E + lane];
    const float* __restrict__ W = WR + (size_t)r * D_E * D_E;
    float ah = 0.f, at = 0.f;
#pragma unroll 8
    for (int k = 0; k < D_E; ++k) {
        float hb = __shfl(h, k, 64);
        float tb = __shfl(t, k, 64);
        float w = W[k * D_E + lane];     // coalesced 256B row, L2-resident
        ah = fmaf(hb, w, ah);
        at = fmaf(tb, w, at);
    }
    float m = ah * tanhf(at + rv);
    // wave reduction
#pragma unroll
    for (int off = 32; off; off >>= 1) m += __shfl_xor(m, off, 64);
    if (lane == 0) att[wid] = m;
}

// ---------------------------------------------------------------------------
// Stage 5: per-dst-node online softmax + message aggregation + fused MLP.
// One wave per node; lane = feature dim.
__global__ __launch_bounds__(256) void agg_kernel(const float* __restrict__ ent,
                                                  const int* __restrict__ offsets,
                                                  const int* __restrict__ eids,
                                                  const int* __restrict__ src,
                                                  const float* __restrict__ att,
                                                  const float* __restrict__ W1,
                                                  const float* __restrict__ b1,
                                                  const float* __restrict__ W2,
                                                  const float* __restrict__ b2,
                                                  float* __restrict__ out, int n) {
    int v = (blockIdx.x * blockDim.x + threadIdx.x) >> 6;
    int lane = threadIdx.x & 63;
    if (v >= n) return;
    int o0 = offsets[v];
    int o1 = offsets[v + 1];
    float m = -INFINITY, l = 0.f, acc = 0.f;
    for (int k = o0; k < o1; ++k) {
        int e = eids[k];
        float a = att[e];
        int s = src[e];
        float x = ent[s * D_E + lane];
        float nm = fmaxf(m, a);
        float scale = __expf(m - nm);    // first iter: expf(-inf) = 0
        float p = __expf(a - nm);
        l = l * scale + p;
        acc = acc * scale + p * x;
        m = nm;
    }
    float Nh = (o1 > o0) ? (acc / l) : 0.f;
    float node = ent[v * D_E + lane];
    float x1 = node + Nh;   // bi-interaction: sum branch
    float x2 = node * Nh;   // bi-interaction: product branch
    // lanes 0..31 compute out1[j], lanes 32..63 compute out2[j]
    const float* __restrict__ Wsel = (lane < 32) ? W1 : W2;
    int j = lane & 31;
    float bias = (lane < 32) ? b1[j] : b2[j];
    float o = 0.f;
#pragma unroll 8
    for (int k = 0; k < D_E; ++k) {
        float xb1 = __shfl(x1, k, 64);
        float xb2 = __shfl(x2, k, 64);
        float xb = (lane < 32) ? xb1 : xb2;
        o = fmaf(xb, Wsel[k * D_OUT + j], o);
    }
    o += bias;
    float lr = (o > 0.f) ? o : 0.01f * o;            // leaky_relu slope 0.01
    float other = __shfl_xor(lr, 32, 64);            // pair out1[j] with out2[j]
    if (lane < 32) out[v * D_OUT + lane] = lr + other;
}

// ---------------------------------------------------------------------------
extern "C" void kernel_launch(void* const* d_in, const int* in_sizes, int n_in,
                              void* d_out, int out_size, void* d_ws, size_t ws_size,
                              hipStream_t stream) {
    const float* ent = (const float*)d_in[0];
    const float* rel = (const float*)d_in[1];
    const float* WR  = (const float*)d_in[2];
    const float* W1  = (const float*)d_in[3];
    const float* b1  = (const float*)d_in[4];
    const float* W2  = (const float*)d_in[5];
    const float* b2  = (const float*)d_in[6];
    const int* src   = (const int*)d_in[7];
    const int* dst   = (const int*)d_in[8];
    const int* ety   = (const int*)d_in[9];
    float* out       = (float*)d_out;

    const int E = in_sizes[7];          // 1,000,000 edges
    const int N = in_sizes[0] / D_E;    // 50,000 nodes

    // workspace carve-up
    char* ws = (char*)d_ws;
    float* att   = (float*)ws;                       // E floats
    int* counts  = (int*)(ws + (size_t)E * 4);       // N
    int* offsets = counts + N;                       // N+1
    int* cursor  = offsets + N + 1;                  // N
    int* eids    = cursor + N;                       // E

    hipMemsetAsync(counts, 0, (size_t)N * 4, stream);
    hist_kernel<<<(E + 255) / 256, 256, 0, stream>>>(dst, counts, E);
    scan_kernel<<<1, 1024, 0, stream>>>(counts, offsets, cursor, N);
    scatter_kernel<<<(E + 255) / 256, 256, 0, stream>>>(dst, cursor, eids, E);
    att_kernel<<<(E + 3) / 4, 256, 0, stream>>>(ent, rel, WR, src, dst, ety, att, E);
    agg_kernel<<<(N + 3) / 4, 256, 0, stream>>>(ent, offsets, eids, src, att,
                                                W1, b1, W2, b2, out, N);
}

// Round 2
// 884.303 us; speedup vs baseline: 1.9604x; 1.9604x over previous
//
#include <hip/hip_runtime.h>
#include <math.h>

#define NREL 16
#define DE 64
#define DOUT 32

__device__ __forceinline__ float tanh_fast(float x) {
    // tanh(x) = 1 - 2/(exp(2x)+1); exp overflow -> +/-1 correctly
    float e = __expf(2.0f * x);
    return fmaf(-2.0f, __builtin_amdgcn_rcpf(e + 1.0f), 1.0f);
}

// ---------------------------------------------------------------------------
// CSR build: histogram -> scan -> scatter
__global__ __launch_bounds__(256) void hist_kernel(const int* __restrict__ dst,
                                                   int* __restrict__ counts, int E) {
    int i = blockIdx.x * blockDim.x + threadIdx.x;
    if (i < E) atomicAdd(&counts[dst[i]], 1);
}

__global__ __launch_bounds__(1024) void scan_kernel(const int* __restrict__ counts,
                                                    int* __restrict__ offsets,
                                                    int* __restrict__ cursor, int n) {
    __shared__ int lds[1024];
    int t = threadIdx.x;
    int C = (n + 1023) >> 10;
    int base = t * C;
    int end = min(base + C, n);
    int s = 0;
    for (int i = base; i < end; ++i) s += counts[i];
    lds[t] = s;
    __syncthreads();
    for (int off = 1; off < 1024; off <<= 1) {
        int v = (t >= off) ? lds[t - off] : 0;
        __syncthreads();
        lds[t] += v;
        __syncthreads();
    }
    int run = (t == 0) ? 0 : lds[t - 1];
    for (int i = base; i < end; ++i) {
        offsets[i] = run;
        cursor[i] = run;
        run += counts[i];
    }
    if (t == 1023) offsets[n] = lds[1023];
}

__global__ __launch_bounds__(256) void scatter_kernel(const int* __restrict__ dst,
                                                      int* __restrict__ cursor,
                                                      int* __restrict__ eids, int E) {
    int i = blockIdx.x * blockDim.x + threadIdx.x;
    if (i < E) {
        int pos = atomicAdd(&cursor[dst[i]], 1);
        eids[pos] = i;
    }
}

// ---------------------------------------------------------------------------
// Tiny transpose: WT[r][j][k] = WR[r][k][j]
__global__ __launch_bounds__(256) void wtrans_kernel(const float* __restrict__ WR,
                                                     float* __restrict__ WT, int tot) {
    int i = blockIdx.x * 256 + threadIdx.x;
    if (i < tot) {
        int r = i >> 12, rem = i & 4095, j = rem >> 6, k = rem & 63;
        WT[i] = WR[(r << 12) + (k << 6) + j];
    }
}

// ---------------------------------------------------------------------------
// Q[r][n][k] = sum_j WR[r][k][j] * tanh( sum_kk ent[n][kk]*WR[r][kk][j] + rel[r][j] )
// One wave per (64-node tile, relation). lane = node. All j/k outputs in regs.
// W rows are wave-uniform -> scalar loads (SGPR operand of v_fmac).
__global__ __launch_bounds__(256) void projq_kernel(const float* __restrict__ ent,
                                                    const float* __restrict__ rel,
                                                    const float* __restrict__ WR,
                                                    const float* __restrict__ WT,
                                                    float* __restrict__ Q,
                                                    int N, int totalUnits) {
    __shared__ float tl[4 * DE * DE];     // per-wave 64x64 t~ slice (thread-private cols)
    int lane = threadIdx.x & 63;
    int wid = threadIdx.x >> 6;
    int unit = blockIdx.x * 4 + wid;
    if (unit >= totalUnits) return;       // whole-wave uniform exit
    int r    = __builtin_amdgcn_readfirstlane(unit & (NREL - 1));
    int tile = __builtin_amdgcn_readfirstlane(unit >> 4);
    int n = tile * 64 + lane;
    bool valid = (n < N);
    const float* __restrict__ entp = ent + (size_t)(valid ? n : 0) * DE;
    const float* __restrict__ Wr   = WR + (size_t)r * DE * DE;   // [k][j]
    const float* __restrict__ WTr  = WT + (size_t)r * DE * DE;   // [j][k]
    const float* __restrict__ relr = rel + r * DE;

    // phase 1: P[j] = sum_k ent[n][k] * W[k][j]
    float acc[DE];
#pragma unroll
    for (int j = 0; j < DE; ++j) acc[j] = 0.f;
    float ecur = entp[0];
    for (int k = 0; k < DE; ++k) {
        float enext = (k < DE - 1) ? entp[k + 1] : 0.f;
        const float* __restrict__ wrow = Wr + k * DE;
#pragma unroll
        for (int j = 0; j < DE; ++j) acc[j] = fmaf(ecur, wrow[j], acc[j]);
        ecur = enext;
    }
    // phase 2: t~[j] = tanh(P[j] + rel[j])  -> private LDS column
    float* tcol = tl + wid * (DE * DE) + lane;
#pragma unroll
    for (int j = 0; j < DE; ++j) tcol[j * DE] = tanh_fast(acc[j] + relr[j]);
    // phase 3: Q[k] = sum_j t~[j] * WT[j][k]
    float q[DE];
#pragma unroll
    for (int k = 0; k < DE; ++k) q[k] = 0.f;
    for (int j = 0; j < DE; ++j) {
        float tj = tcol[j * DE];
        const float* __restrict__ wtrow = WTr + j * DE;
#pragma unroll
        for (int k = 0; k < DE; ++k) q[k] = fmaf(tj, wtrow[k], q[k]);
    }
    if (valid) {
        float* qp = Q + ((size_t)r * N + n) * DE;
#pragma unroll
        for (int k = 0; k < DE; k += 4) {
            float4 v = make_float4(q[k], q[k + 1], q[k + 2], q[k + 3]);
            *(float4*)(qp + k) = v;
        }
    }
}

// ---------------------------------------------------------------------------
// att[e] = ent[src] . Q[etype, dst] — 16 lanes per edge, DPP-only reduction
__global__ __launch_bounds__(256) void att2_kernel(const float* __restrict__ ent,
                                                   const float* __restrict__ Q,
                                                   const int* __restrict__ src,
                                                   const int* __restrict__ dst,
                                                   const int* __restrict__ etype,
                                                   float* __restrict__ att, int E, int N) {
    int t = blockIdx.x * 256 + threadIdx.x;
    int e = t >> 4;
    int l = threadIdx.x & 15;
    if (e >= E) return;
    int s = src[e], d = dst[e], r = etype[e];
    float4 a = ((const float4*)(ent + (size_t)s * DE))[l];
    float4 b = ((const float4*)(Q + ((size_t)r * N + d) * DE))[l];
    float m = a.x * b.x + a.y * b.y + a.z * b.z + a.w * b.w;
    m += __shfl_xor(m, 1, 16);
    m += __shfl_xor(m, 2, 16);
    m += __shfl_xor(m, 4, 16);
    m += __shfl_xor(m, 8, 16);
    if (l == 0) att[e] = m;
}

// ---------------------------------------------------------------------------
// Fallback (slow) att: one wave per edge, shfl-broadcast matvec
__global__ __launch_bounds__(256) void att_kernel(const float* __restrict__ ent,
                                                  const float* __restrict__ rel,
                                                  const float* __restrict__ WR,
                                                  const int* __restrict__ src,
                                                  const int* __restrict__ dst,
                                                  const int* __restrict__ etype,
                                                  float* __restrict__ att, int E) {
    int wid = (blockIdx.x * blockDim.x + threadIdx.x) >> 6;
    int lane = threadIdx.x & 63;
    if (wid >= E) return;
    int s = src[wid];
    int d = dst[wid];
    int r = etype[wid];
    float h = ent[s * DE + lane];
    float t = ent[d * DE + lane];
    float rv = rel[r * DE + lane];
    const float* __restrict__ W = WR + (size_t)r * DE * DE;
    float ah = 0.f, at = 0.f;
#pragma unroll 8
    for (int k = 0; k < DE; ++k) {
        float hb = __shfl(h, k, 64);
        float tb = __shfl(t, k, 64);
        float w = W[k * DE + lane];
        ah = fmaf(hb, w, ah);
        at = fmaf(tb, w, at);
    }
    float m = ah * tanhf(at + rv);
#pragma unroll
    for (int off = 32; off; off >>= 1) m += __shfl_xor(m, off, 64);
    if (lane == 0) att[wid] = m;
}

// ---------------------------------------------------------------------------
// per-dst online softmax + aggregation + fused bi-interaction MLP
__global__ __launch_bounds__(256) void agg_kernel(const float* __restrict__ ent,
                                                  const int* __restrict__ offsets,
                                                  const int* __restrict__ eids,
                                                  const int* __restrict__ src,
                                                  const float* __restrict__ att,
                                                  const float* __restrict__ W1,
                                                  const float* __restrict__ b1,
                                                  const float* __restrict__ W2,
                                                  const float* __restrict__ b2,
                                                  float* __restrict__ out, int n) {
    int v = (blockIdx.x * blockDim.x + threadIdx.x) >> 6;
    int lane = threadIdx.x & 63;
    if (v >= n) return;
    int o0 = offsets[v];
    int o1 = offsets[v + 1];
    float m = -INFINITY, l = 0.f, acc = 0.f;
    for (int k = o0; k < o1; ++k) {
        int e = eids[k];
        float a = att[e];
        int s = src[e];
        float x = ent[s * DE + lane];
        float nm = fmaxf(m, a);
        float scale = __expf(m - nm);
        float p = __expf(a - nm);
        l = l * scale + p;
        acc = acc * scale + p * x;
        m = nm;
    }
    float Nh = (o1 > o0) ? (acc / l) : 0.f;
    float node = ent[v * DE + lane];
    float x1 = node + Nh;
    float x2 = node * Nh;
    const float* __restrict__ Wsel = (lane < 32) ? W1 : W2;
    int j = lane & 31;
    float bias = (lane < 32) ? b1[j] : b2[j];
    float o = 0.f;
#pragma unroll 8
    for (int k = 0; k < DE; ++k) {
        float xb1 = __shfl(x1, k, 64);
        float xb2 = __shfl(x2, k, 64);
        float xb = (lane < 32) ? xb1 : xb2;
        o = fmaf(xb, Wsel[k * DOUT + j], o);
    }
    o += bias;
    float lr = (o > 0.f) ? o : 0.01f * o;
    float other = __shfl_xor(lr, 32, 64);
    if (lane < 32) out[v * DOUT + lane] = lr + other;
}

// ---------------------------------------------------------------------------
extern "C" void kernel_launch(void* const* d_in, const int* in_sizes, int n_in,
                              void* d_out, int out_size, void* d_ws, size_t ws_size,
                              hipStream_t stream) {
    const float* ent = (const float*)d_in[0];
    const float* rel = (const float*)d_in[1];
    const float* WR  = (const float*)d_in[2];
    const float* W1  = (const float*)d_in[3];
    const float* b1  = (const float*)d_in[4];
    const float* W2  = (const float*)d_in[5];
    const float* b2  = (const float*)d_in[6];
    const int* src   = (const int*)d_in[7];
    const int* dst   = (const int*)d_in[8];
    const int* ety   = (const int*)d_in[9];
    float* out       = (float*)d_out;

    const int E = in_sizes[7];
    const int N = in_sizes[0] / DE;

    size_t qElems = (size_t)NREL * N * DE;
    size_t wtElems = (size_t)NREL * DE * DE;
    size_t needFast = (qElems + (size_t)E + wtElems) * 4
                    + ((size_t)3 * N + 1 + E) * 4;

    char* ws = (char*)d_ws;
    if (ws_size >= needFast) {
        // fast path layout: Q | att | WT | counts | offsets | cursor | eids
        float* Q    = (float*)ws;
        float* att  = Q + qElems;
        float* WT   = att + E;
        int* counts = (int*)(WT + wtElems);
        int* offsets= counts + N;
        int* cursor = offsets + N + 1;
        int* eids   = cursor + N;

        hipMemsetAsync(counts, 0, (size_t)N * 4, stream);
        wtrans_kernel<<<(int)((wtElems + 255) / 256), 256, 0, stream>>>(WR, WT, (int)wtElems);
        hist_kernel<<<(E + 255) / 256, 256, 0, stream>>>(dst, counts, E);
        scan_kernel<<<1, 1024, 0, stream>>>(counts, offsets, cursor, N);
        scatter_kernel<<<(E + 255) / 256, 256, 0, stream>>>(dst, cursor, eids, E);
        int totalUnits = ((N + 63) / 64) * NREL;
        projq_kernel<<<(totalUnits + 3) / 4, 256, 0, stream>>>(ent, rel, WR, WT, Q, N, totalUnits);
        att2_kernel<<<(E + 15) / 16, 256, 0, stream>>>(ent, Q, src, dst, ety, att, E, N);
        agg_kernel<<<(N + 3) / 4, 256, 0, stream>>>(ent, offsets, eids, src, att,
                                                    W1, b1, W2, b2, out, N);
    } else {
        // fallback: previous round's path
        float* att   = (float*)ws;
        int* counts  = (int*)(ws + (size_t)E * 4);
        int* offsets = counts + N;
        int* cursor  = offsets + N + 1;
        int* eids    = cursor + N;

        hipMemsetAsync(counts, 0, (size_t)N * 4, stream);
        hist_kernel<<<(E + 255) / 256, 256, 0, stream>>>(dst, counts, E);
        scan_kernel<<<1, 1024, 0, stream>>>(counts, offsets, cursor, N);
        scatter_kernel<<<(E + 255) / 256, 256, 0, stream>>>(dst, cursor, eids, E);
        att_kernel<<<(E + 3) / 4, 256, 0, stream>>>(ent, rel, WR, src, dst, ety, att, E);
        agg_kernel<<<(N + 3) / 4, 256, 0, stream>>>(ent, offsets, eids, src, att,
                                                    W1, b1, W2, b2, out, N);
    }
}

// Round 3
// 526.656 us; speedup vs baseline: 3.2917x; 1.6791x over previous
//
#include <hip/hip_runtime.h>
#include <math.h>

#define NREL 16
#define DE 64
#define DOUT 32

typedef __attribute__((ext_vector_type(8))) short bf16x8;
typedef __attribute__((ext_vector_type(16))) float f32x16;

__device__ __forceinline__ short f2bf(float f) {
    unsigned u = __builtin_bit_cast(unsigned, f);
    unsigned r = (u + 0x7FFFu + ((u >> 16) & 1u)) >> 16;
    return (short)r;
}

__device__ __forceinline__ float tanh_fast(float x) {
    float e = __expf(2.0f * x);
    return fmaf(-2.0f, __builtin_amdgcn_rcpf(e + 1.0f), 1.0f);
}

// ---------------------------------------------------------------------------
// CSR build: histogram -> scan -> scatter
__global__ __launch_bounds__(256) void hist_kernel(const int* __restrict__ dst,
                                                   int* __restrict__ counts, int E) {
    int i = blockIdx.x * blockDim.x + threadIdx.x;
    if (i < E) atomicAdd(&counts[dst[i]], 1);
}

__global__ __launch_bounds__(1024) void scan_kernel(const int* __restrict__ counts,
                                                    int* __restrict__ offsets,
                                                    int* __restrict__ cursor, int n) {
    __shared__ int lds[1024];
    int t = threadIdx.x;
    int C = (n + 1023) >> 10;
    int base = t * C;
    int end = min(base + C, n);
    int s = 0;
    for (int i = base; i < end; ++i) s += counts[i];
    lds[t] = s;
    __syncthreads();
    for (int off = 1; off < 1024; off <<= 1) {
        int v = (t >= off) ? lds[t - off] : 0;
        __syncthreads();
        lds[t] += v;
        __syncthreads();
    }
    int run = (t == 0) ? 0 : lds[t - 1];
    for (int i = base; i < end; ++i) {
        offsets[i] = run;
        cursor[i] = run;
        run += counts[i];
    }
    if (t == 1023) offsets[n] = lds[1023];
}

__global__ __launch_bounds__(256) void scatter_kernel(const int* __restrict__ dst,
                                                      int* __restrict__ cursor,
                                                      int* __restrict__ eids, int E) {
    int i = blockIdx.x * blockDim.x + threadIdx.x;
    if (i < E) {
        int pos = atomicAdd(&cursor[dst[i]], 1);
        eids[pos] = i;
    }
}

// ---------------------------------------------------------------------------
// Convert W_R to bf16 in both orientations:
//   Wbf[r][k][j]  (serves GEMM2's B operand: memory [n=kout][kdim=j])
//   WTbf[r][j][k] (serves GEMM1's B operand: memory [n=j][kdim=k])
__global__ __launch_bounds__(256) void wcvt_kernel(const float* __restrict__ WR,
                                                   short* __restrict__ Wbf,
                                                   short* __restrict__ WTbf) {
    int i = blockIdx.x * 256 + threadIdx.x;     // 16*64*64 = 65536 threads
    int r = i >> 12, k = (i >> 6) & 63, j = i & 63;
    short b = f2bf(WR[i]);
    Wbf[i] = b;
    WTbf[(r << 12) + (j << 6) + k] = b;
}

// ---------------------------------------------------------------------------
// MFMA projq: per (32-node tile, relation) wave:
//   T = tanh(ent_tile @ W_r + rel_r)   (32x64)
//   Qt = T @ W_r^T                     (32x64) -> Q[node][r][k]
// A/B lane maps for mfma_f32_32x32x16_bf16:
//   A[m][k]: m=lane&31, k=(lane>>5)*8+i ; B[k][n]: n=lane&31, k=(lane>>5)*8+i
//   C/D: col=lane&31, row=(reg&3)+8*(reg>>2)+4*(lane>>5)   [HW-verified]
__global__ __launch_bounds__(256) void projq_kernel(const float* __restrict__ ent,
                                                    const float* __restrict__ rel,
                                                    const short* __restrict__ Wbf,
                                                    const short* __restrict__ WTbf,
                                                    float* __restrict__ Q, int N) {
    __shared__ short Tl[4 * 32 * 64];           // 4 waves x 4KB, XOR-swizzled
    int lane = threadIdx.x & 63;
    int wid = threadIdx.x >> 6;
    int r = blockIdx.y;
    int m0 = (blockIdx.x * 4 + wid) * 32;
    if (m0 >= N) return;                        // wave-uniform exit
    int hi = lane >> 5;
    int lo = lane & 31;

    // A fragments: ent rows (f32 -> bf16 in flight)
    int arow = m0 + lo;
    if (arow >= N) arow = N - 1;
    const float* ap = ent + (size_t)arow * DE + hi * 8;
    bf16x8 A[4];
#pragma unroll
    for (int kk = 0; kk < 4; ++kk) {
        float4 f0 = *(const float4*)(ap + kk * 16);
        float4 f1 = *(const float4*)(ap + kk * 16 + 4);
        bf16x8 a;
        a[0] = f2bf(f0.x); a[1] = f2bf(f0.y); a[2] = f2bf(f0.z); a[3] = f2bf(f0.w);
        a[4] = f2bf(f1.x); a[5] = f2bf(f1.y); a[6] = f2bf(f1.z); a[7] = f2bf(f1.w);
        A[kk] = a;
    }

    const short* wtb = WTbf + ((size_t)r << 12);
    const short* wb  = Wbf  + ((size_t)r << 12);

    // GEMM1: P = ent @ W_r   (B from WTbf[j][k]: 16B contiguous per lane)
    f32x16 acc0 = {}, acc1 = {};
#pragma unroll
    for (int kk = 0; kk < 4; ++kk) {
        bf16x8 b0 = *(const bf16x8*)(wtb + lo * DE + kk * 16 + hi * 8);
        bf16x8 b1 = *(const bf16x8*)(wtb + (lo + 32) * DE + kk * 16 + hi * 8);
        acc0 = __builtin_amdgcn_mfma_f32_32x32x16_bf16(A[kk], b0, acc0, 0, 0, 0);
        acc1 = __builtin_amdgcn_mfma_f32_32x32x16_bf16(A[kk], b1, acc1, 0, 0, 0);
    }

    // tanh(P + rel) -> bf16 -> swizzled LDS (C-layout -> A-layout crossing)
    float rv0 = rel[r * DE + lo];
    float rv1 = rel[r * DE + 32 + lo];
    short* tb = Tl + wid * 2048;
#pragma unroll
    for (int i = 0; i < 16; ++i) {
        int row = (i & 3) + 8 * (i >> 2) + 4 * hi;
        int sw = (row & 7) << 3;                // 8-short (16B) granular XOR
        float t0 = tanh_fast(acc0[i] + rv0);
        float t1 = tanh_fast(acc1[i] + rv1);
        tb[(row * DE + lo) ^ sw] = f2bf(t0);
        tb[(row * DE + 32 + lo) ^ sw] = f2bf(t1);
    }

    // A2 fragments from LDS T tile
    bf16x8 A2[4];
#pragma unroll
    for (int kk = 0; kk < 4; ++kk) {
        int row = lo;
        A2[kk] = *(const bf16x8*)(tb + ((row * DE + kk * 16 + hi * 8) ^ ((row & 7) << 3)));
    }

    // GEMM2: Qt = T @ W_r^T   (B from Wbf[k][j]: 16B contiguous per lane)
    f32x16 q0 = {}, q1 = {};
#pragma unroll
    for (int kk = 0; kk < 4; ++kk) {
        bf16x8 b0 = *(const bf16x8*)(wb + lo * DE + kk * 16 + hi * 8);
        bf16x8 b1 = *(const bf16x8*)(wb + (lo + 32) * DE + kk * 16 + hi * 8);
        q0 = __builtin_amdgcn_mfma_f32_32x32x16_bf16(A2[kk], b0, q0, 0, 0, 0);
        q1 = __builtin_amdgcn_mfma_f32_32x32x16_bf16(A2[kk], b1, q1, 0, 0, 0);
    }

    // store Q[node][r][k], 128B contiguous per lane-half
#pragma unroll
    for (int i = 0; i < 16; ++i) {
        int node = m0 + (i & 3) + 8 * (i >> 2) + 4 * hi;
        if (node < N) {
            float* qp = Q + (((size_t)node * NREL + r) << 6);
            qp[lo] = q0[i];
            qp[32 + lo] = q1[i];
        }
    }
}

// ---------------------------------------------------------------------------
// Fused: per-dst att dot (wave reduce) + online softmax + aggregation + MLP
__global__ __launch_bounds__(256) void agg_kernel(const float* __restrict__ ent,
                                                  const float* __restrict__ Q,
                                                  const int* __restrict__ offsets,
                                                  const int* __restrict__ eids,
                                                  const int* __restrict__ src,
                                                  const int* __restrict__ etype,
                                                  const float* __restrict__ W1,
                                                  const float* __restrict__ b1,
                                                  const float* __restrict__ W2,
                                                  const float* __restrict__ b2,
                                                  float* __restrict__ out, int n) {
    int v = (blockIdx.x * blockDim.x + threadIdx.x) >> 6;
    int lane = threadIdx.x & 63;
    if (v >= n) return;
    int o0 = offsets[v], o1 = offsets[v + 1];
    const float* qv = Q + ((size_t)v << 10);    // [r][64] block, 4KB
    float m = -INFINITY, l = 0.f, acc = 0.f;
    for (int k = o0; k < o1; ++k) {
        int e = eids[k];
        int s = src[e];
        int r = etype[e];
        float x = ent[(size_t)s * DE + lane];
        float qq = qv[(r << 6) + lane];
        float p = x * qq;                        // att dot, full-wave reduce
        p += __shfl_xor(p, 1);
        p += __shfl_xor(p, 2);
        p += __shfl_xor(p, 4);
        p += __shfl_xor(p, 8);
        p += __shfl_xor(p, 16);
        p += __shfl_xor(p, 32);
        float nm = fmaxf(m, p);
        float sc = __expf(m - nm);
        float pe = __expf(p - nm);
        l = l * sc + pe;
        acc = acc * sc + pe * x;
        m = nm;
    }
    float Nh = (o1 > o0) ? (acc / l) : 0.f;
    float node = ent[(size_t)v * DE + lane];
    float x1 = node + Nh;
    float x2 = node * Nh;
    const float* __restrict__ Wsel = (lane < 32) ? W1 : W2;
    int j = lane & 31;
    float bias = (lane < 32) ? b1[j] : b2[j];
    float o = 0.f;
#pragma unroll 8
    for (int k = 0; k < DE; ++k) {
        float xb1 = __shfl(x1, k, 64);
        float xb2 = __shfl(x2, k, 64);
        float xb = (lane < 32) ? xb1 : xb2;
        o = fmaf(xb, Wsel[k * DOUT + j], o);
    }
    o += bias;
    float lr = (o > 0.f) ? o : 0.01f * o;
    float other = __shfl_xor(lr, 32, 64);
    if (lane < 32) out[v * DOUT + lane] = lr + other;
}

// ---------------------------------------------------------------------------
extern "C" void kernel_launch(void* const* d_in, const int* in_sizes, int n_in,
                              void* d_out, int out_size, void* d_ws, size_t ws_size,
                              hipStream_t stream) {
    const float* ent = (const float*)d_in[0];
    const float* rel = (const float*)d_in[1];
    const float* WR  = (const float*)d_in[2];
    const float* W1  = (const float*)d_in[3];
    const float* b1  = (const float*)d_in[4];
    const float* W2  = (const float*)d_in[5];
    const float* b2  = (const float*)d_in[6];
    const int* src   = (const int*)d_in[7];
    const int* dst   = (const int*)d_in[8];
    const int* ety   = (const int*)d_in[9];
    float* out       = (float*)d_out;

    const int E = in_sizes[7];
    const int N = in_sizes[0] / DE;

    size_t qElems = (size_t)N * NREL * DE;       // 51.2M f32 = 204.8 MB
    size_t wElems = (size_t)NREL * DE * DE;      // 65536 bf16

    char* ws = (char*)d_ws;
    float* Q     = (float*)ws;
    short* Wbf   = (short*)(Q + qElems);
    short* WTbf  = Wbf + wElems;
    int* counts  = (int*)(WTbf + wElems);
    int* offsets = counts + N;
    int* cursor  = offsets + N + 1;
    int* eids    = cursor + N;
    size_t need  = (size_t)((char*)(eids + E) - ws);
    if (ws_size < need) return;                  // ws known >= 213.5MB; need ~210MB

    hipMemsetAsync(counts, 0, (size_t)N * 4, stream);
    wcvt_kernel<<<(int)(wElems / 256), 256, 0, stream>>>(WR, Wbf, WTbf);
    hist_kernel<<<(E + 255) / 256, 256, 0, stream>>>(dst, counts, E);
    scan_kernel<<<1, 1024, 0, stream>>>(counts, offsets, cursor, N);
    scatter_kernel<<<(E + 255) / 256, 256, 0, stream>>>(dst, cursor, eids, E);
    projq_kernel<<<dim3((N + 127) / 128, NREL), 256, 0, stream>>>(ent, rel, Wbf, WTbf, Q, N);
    agg_kernel<<<(N + 3) / 4, 256, 0, stream>>>(ent, Q, offsets, eids, src, ety,
                                                W1, b1, W2, b2, out, N);
}

// Round 4
// 352.853 us; speedup vs baseline: 4.9131x; 1.4926x over previous
//
#include <hip/hip_runtime.h>
#include <math.h>

#define NREL 16
#define DE 64
#define DOUT 32

typedef __attribute__((ext_vector_type(8))) short bf16x8;
typedef __attribute__((ext_vector_type(16))) float f32x16;

__device__ __forceinline__ short f2bf(float f) {
    unsigned u = __builtin_bit_cast(unsigned, f);
    unsigned r = (u + 0x7FFFu + ((u >> 16) & 1u)) >> 16;
    return (short)r;
}
__device__ __forceinline__ float bf2f(short s) {
    unsigned u = ((unsigned)(unsigned short)s) << 16;
    return __builtin_bit_cast(float, u);
}
__device__ __forceinline__ float tanh_fast(float x) {
    float e = __expf(2.0f * x);
    return fmaf(-2.0f, __builtin_amdgcn_rcpf(e + 1.0f), 1.0f);
}

// ---------------------------------------------------------------------------
// CSR build
__global__ __launch_bounds__(256) void hist_kernel(const int* __restrict__ dst,
                                                   int* __restrict__ counts, int E) {
    int i = blockIdx.x * blockDim.x + threadIdx.x;
    if (i < E) atomicAdd(&counts[dst[i]], 1);
}

__global__ __launch_bounds__(1024) void scan_kernel(const int* __restrict__ counts,
                                                    int* __restrict__ offsets,
                                                    int* __restrict__ cursor, int n) {
    __shared__ int lds[1024];
    int t = threadIdx.x;
    int C = (n + 1023) >> 10;
    int base = t * C;
    int end = min(base + C, n);
    int s = 0;
    for (int i = base; i < end; ++i) s += counts[i];
    lds[t] = s;
    __syncthreads();
    for (int off = 1; off < 1024; off <<= 1) {
        int v = (t >= off) ? lds[t - off] : 0;
        __syncthreads();
        lds[t] += v;
        __syncthreads();
    }
    int run = (t == 0) ? 0 : lds[t - 1];
    for (int i = base; i < end; ++i) {
        offsets[i] = run;
        cursor[i] = run;
        run += counts[i];
    }
    if (t == 1023) offsets[n] = lds[1023];
}

// scatter src/etype into CSR order (removes eids indirection in agg)
__global__ __launch_bounds__(256) void scatter_kernel(const int* __restrict__ dst,
                                                      const int* __restrict__ src,
                                                      const int* __restrict__ etype,
                                                      int* __restrict__ cursor,
                                                      int* __restrict__ srcs,
                                                      int* __restrict__ etys, int E) {
    int i = blockIdx.x * blockDim.x + threadIdx.x;
    if (i < E) {
        int pos = atomicAdd(&cursor[dst[i]], 1);
        srcs[pos] = src[i];
        etys[pos] = etype[i];
    }
}

// ---------------------------------------------------------------------------
__global__ __launch_bounds__(256) void entcvt_kernel(const float* __restrict__ ent,
                                                     short* __restrict__ entbf, int tot) {
    int i = blockIdx.x * 256 + threadIdx.x;
    if (i < tot) entbf[i] = f2bf(ent[i]);
}

__global__ __launch_bounds__(256) void wcvt_kernel(const float* __restrict__ WR,
                                                   short* __restrict__ Wbf,
                                                   short* __restrict__ WTbf) {
    int i = blockIdx.x * 256 + threadIdx.x;     // 65536 threads
    int r = i >> 12, k = (i >> 6) & 63, j = i & 63;
    short b = f2bf(WR[i]);
    Wbf[i] = b;
    WTbf[(r << 12) + (j << 6) + k] = b;
}

// ---------------------------------------------------------------------------
// MFMA projq: per wave: 32-node tile, loop over 4 relations (A reused).
// Qbf[node][r][k] = (tanh(ent W_r + rel_r) W_r^T)[node][k]  in bf16
__global__ __launch_bounds__(256) void projq_kernel(const short* __restrict__ entbf,
                                                    const float* __restrict__ rel,
                                                    const short* __restrict__ Wbf,
                                                    const short* __restrict__ WTbf,
                                                    short* __restrict__ Qbf, int N) {
    __shared__ short Tl[4 * 2048];   // per-wave swizzled tanh tile (4KB)
    __shared__ short Tq[4 * 2048];   // per-wave Q repack tile (4KB)
    int lane = threadIdx.x & 63;
    int wid = threadIdx.x >> 6;
    int m0 = (blockIdx.x * 4 + wid) * 32;
    if (m0 >= N) return;             // wave-uniform exit
    int hi = lane >> 5;
    int lo = lane & 31;

    int arow = m0 + lo;
    if (arow >= N) arow = N - 1;
    const short* ap = entbf + ((size_t)arow << 6) + hi * 8;
    bf16x8 A[4];
#pragma unroll
    for (int kk = 0; kk < 4; ++kk) A[kk] = *(const bf16x8*)(ap + kk * 16);

    short* tb = Tl + wid * 2048;
    short* tq = Tq + wid * 2048;

    for (int rr = 0; rr < 4; ++rr) {
        int r = blockIdx.y * 4 + rr;
        const short* wtb = WTbf + ((size_t)r << 12);
        const short* wb  = Wbf  + ((size_t)r << 12);

        // GEMM1: P = ent @ W_r
        f32x16 acc0 = {}, acc1 = {};
#pragma unroll
        for (int kk = 0; kk < 4; ++kk) {
            bf16x8 b0 = *(const bf16x8*)(wtb + lo * DE + kk * 16 + hi * 8);
            bf16x8 b1 = *(const bf16x8*)(wtb + (lo + 32) * DE + kk * 16 + hi * 8);
            acc0 = __builtin_amdgcn_mfma_f32_32x32x16_bf16(A[kk], b0, acc0, 0, 0, 0);
            acc1 = __builtin_amdgcn_mfma_f32_32x32x16_bf16(A[kk], b1, acc1, 0, 0, 0);
        }
        // tanh(P + rel) -> bf16 -> swizzled LDS (C-layout -> A-layout)
        float rv0 = rel[r * DE + lo];
        float rv1 = rel[r * DE + 32 + lo];
#pragma unroll
        for (int i = 0; i < 16; ++i) {
            int row = (i & 3) + 8 * (i >> 2) + 4 * hi;
            int sw = (row & 7) << 3;
            tb[(row * DE + lo) ^ sw] = f2bf(tanh_fast(acc0[i] + rv0));
            tb[(row * DE + 32 + lo) ^ sw] = f2bf(tanh_fast(acc1[i] + rv1));
        }
        bf16x8 A2[4];
#pragma unroll
        for (int kk = 0; kk < 4; ++kk)
            A2[kk] = *(const bf16x8*)(tb + ((lo * DE + kk * 16 + hi * 8) ^ ((lo & 7) << 3)));

        // GEMM2: Qt = T @ W_r^T
        f32x16 q0 = {}, q1 = {};
#pragma unroll
        for (int kk = 0; kk < 4; ++kk) {
            bf16x8 b0 = *(const bf16x8*)(wb + lo * DE + kk * 16 + hi * 8);
            bf16x8 b1 = *(const bf16x8*)(wb + (lo + 32) * DE + kk * 16 + hi * 8);
            q0 = __builtin_amdgcn_mfma_f32_32x32x16_bf16(A2[kk], b0, q0, 0, 0, 0);
            q1 = __builtin_amdgcn_mfma_f32_32x32x16_bf16(A2[kk], b1, q1, 0, 0, 0);
        }
        // repack to row-major bf16 in LDS, then 16B coalesced stores
#pragma unroll
        for (int i = 0; i < 16; ++i) {
            int row = (i & 3) + 8 * (i >> 2) + 4 * hi;
            tq[row * DE + lo] = f2bf(q0[i]);
            tq[row * DE + 32 + lo] = f2bf(q1[i]);
        }
#pragma unroll
        for (int p = 0; p < 4; ++p) {
            int row = p * 8 + (lane >> 3);
            int node = m0 + row;
            bf16x8 vq = *(const bf16x8*)(tq + row * DE + (lane & 7) * 8);
            if (node < N)
                *(bf16x8*)(Qbf + (((size_t)node * NREL + r) << 6) + (lane & 7) * 8) = vq;
        }
    }
}

// ---------------------------------------------------------------------------
// Fused agg: one wave per dst node; 8 edges in flight (8 lanes each),
// depth-1 prefetch, per-group online softmax, 3-step merge, LDS-broadcast MLP.
__global__ __launch_bounds__(256) void agg_kernel(const float* __restrict__ ent,
                                                  const short* __restrict__ entbf,
                                                  const short* __restrict__ Qbf,
                                                  const int* __restrict__ offsets,
                                                  const int* __restrict__ srcs,
                                                  const int* __restrict__ etys,
                                                  const float* __restrict__ W1,
                                                  const float* __restrict__ b1,
                                                  const float* __restrict__ W2,
                                                  const float* __restrict__ b2,
                                                  float* __restrict__ out, int n) {
    __shared__ float xl[4][128];
    int lane = threadIdx.x & 63;
    int wid = threadIdx.x >> 6;
    int v = (blockIdx.x << 2) + wid;
    if (v >= n) return;
    int o0 = offsets[v], o1 = offsets[v + 1];
    int g = lane >> 3, gl = lane & 7;
    const short* qbase = Qbf + ((size_t)v << 10) + gl * 8;

    float m = -INFINITY, l = 0.f;
    float acc[8];
#pragma unroll
    for (int j = 0; j < 8; ++j) acc[j] = 0.f;

    int k = o0 + g;
    bool val = k < o1;
    bf16x8 xv = {}, qv = {};
    if (val) {
        int s = srcs[k];
        int r = etys[k];
        xv = *(const bf16x8*)(entbf + ((size_t)s << 6) + gl * 8);
        qv = *(const bf16x8*)(qbase + (r << 6));
    }
    int iters = (o1 - o0 + 7) >> 3;
    for (int it = 0; it < iters; ++it) {
        // prefetch next group-of-8
        int kn = k + 8;
        bool valn = kn < o1;
        bf16x8 xn = {}, qn = {};
        if (valn) {
            int s = srcs[kn];
            int r = etys[kn];
            xn = *(const bf16x8*)(entbf + ((size_t)s << 6) + gl * 8);
            qn = *(const bf16x8*)(qbase + (r << 6));
        }
        // att dot over 8 lanes
        float xf[8];
        float d = 0.f;
#pragma unroll
        for (int j = 0; j < 8; ++j) {
            xf[j] = bf2f(xv[j]);
            d = fmaf(xf[j], bf2f(qv[j]), d);
        }
        d += __shfl_xor(d, 1);
        d += __shfl_xor(d, 2);
        d += __shfl_xor(d, 4);
        float p = val ? d : -INFINITY;
        // online softmax update (per group)
        float nm = fmaxf(m, p);
        float sc, pe;
        if (nm == -INFINITY) { sc = 0.f; pe = 0.f; }
        else { sc = __expf(m - nm); pe = __expf(p - nm); }
        l = l * sc + pe;
#pragma unroll
        for (int j = 0; j < 8; ++j) acc[j] = fmaf(acc[j], sc, pe * xf[j]);
        m = nm;
        k = kn; val = valn; xv = xn; qv = qn;
    }
    // merge the 8 group-partials (group id = lane bits 3..5)
#pragma unroll
    for (int off = 8; off < 64; off <<= 1) {
        float mo = __shfl_xor(m, off);
        float lo2 = __shfl_xor(l, off);
        float nm = fmaxf(m, mo);
        float s1 = (nm == -INFINITY) ? 0.f : __expf(m - nm);
        float s2 = (nm == -INFINITY) ? 0.f : __expf(mo - nm);
        l = l * s1 + lo2 * s2;
#pragma unroll
        for (int j = 0; j < 8; ++j) {
            float ao = __shfl_xor(acc[j], off);
            acc[j] = acc[j] * s1 + ao * s2;
        }
        m = nm;
    }
    // redistribute Nh (feats gl*8..+7 per lane) -> lane=feat via LDS
    float* xw = &xl[wid][0];
    float invl = (l > 0.f) ? (1.0f / l) : 0.f;
    if (g == 0) {
#pragma unroll
        for (int j = 0; j < 8; ++j) xw[gl * 8 + j] = acc[j] * invl;
    }
    float node = ent[((size_t)v << 6) + lane];
    float Nh = xw[lane];                 // same-wave LDS RAW (compiler waits)
    float x1 = node + Nh;
    float x2 = node * Nh;
    xw[lane] = x1;
    xw[64 + lane] = x2;
    int j = lane & 31;
    const float* __restrict__ Wsel = (lane < 32) ? W1 : W2;
    float bias = (lane < 32) ? b1[j] : b2[j];
    const float* xb = xw + ((lane < 32) ? 0 : 64);
    float o = 0.f;
#pragma unroll 8
    for (int kk = 0; kk < DE; ++kk)
        o = fmaf(xb[kk], Wsel[kk * DOUT + j], o);
    o += bias;
    float lr = (o > 0.f) ? o : 0.01f * o;
    float other = __shfl_xor(lr, 32);
    if (lane < 32) out[(size_t)v * DOUT + lane] = lr + other;
}

// ---------------------------------------------------------------------------
extern "C" void kernel_launch(void* const* d_in, const int* in_sizes, int n_in,
                              void* d_out, int out_size, void* d_ws, size_t ws_size,
                              hipStream_t stream) {
    const float* ent = (const float*)d_in[0];
    const float* rel = (const float*)d_in[1];
    const float* WR  = (const float*)d_in[2];
    const float* W1  = (const float*)d_in[3];
    const float* b1  = (const float*)d_in[4];
    const float* W2  = (const float*)d_in[5];
    const float* b2  = (const float*)d_in[6];
    const int* src   = (const int*)d_in[7];
    const int* dst   = (const int*)d_in[8];
    const int* ety   = (const int*)d_in[9];
    float* out       = (float*)d_out;

    const int E = in_sizes[7];
    const int N = in_sizes[0] / DE;

    size_t qElems  = (size_t)N * NREL * DE;     // 51.2M bf16 = 102.4 MB
    size_t eElems  = (size_t)N * DE;            // 3.2M bf16
    size_t wElems  = (size_t)NREL * DE * DE;    // 65536 bf16

    char* ws = (char*)d_ws;
    short* Qbf   = (short*)ws;
    short* entbf = Qbf + qElems;
    short* Wbf   = entbf + eElems;
    short* WTbf  = Wbf + wElems;
    int* counts  = (int*)(WTbf + wElems);
    int* offsets = counts + N;
    int* cursor  = offsets + N + 1;
    int* srcs    = cursor + N;
    int* etys    = srcs + E;
    size_t need  = (size_t)((char*)(etys + E) - ws);
    if (ws_size < need) return;                 // ~118 MB needed, ~213 MB available

    hipMemsetAsync(counts, 0, (size_t)N * 4, stream);
    entcvt_kernel<<<(int)((eElems + 255) / 256), 256, 0, stream>>>(ent, entbf, (int)eElems);
    wcvt_kernel<<<(int)(wElems / 256), 256, 0, stream>>>(WR, Wbf, WTbf);
    hist_kernel<<<(E + 255) / 256, 256, 0, stream>>>(dst, counts, E);
    scan_kernel<<<1, 1024, 0, stream>>>(counts, offsets, cursor, N);
    scatter_kernel<<<(E + 255) / 256, 256, 0, stream>>>(dst, src, ety, cursor, srcs, etys, E);
    projq_kernel<<<dim3((N + 127) / 128, 4), 256, 0, stream>>>(entbf, rel, Wbf, WTbf, Qbf, N);
    agg_kernel<<<(N + 3) / 4, 256, 0, stream>>>(ent, entbf, Qbf, offsets, srcs, etys,
                                                W1, b1, W2, b2, out, N);
}

// Round 5
// 268.203 us; speedup vs baseline: 6.4638x; 1.3156x over previous
//
#include <hip/hip_runtime.h>
#include <math.h>

#define NREL 16
#define DE 64
#define DOUT 32

typedef __attribute__((ext_vector_type(8))) short bf16x8;
typedef __attribute__((ext_vector_type(16))) float f32x16;

__device__ __forceinline__ short f2bf(float f) {
    unsigned u = __builtin_bit_cast(unsigned, f);
    unsigned r = (u + 0x7FFFu + ((u >> 16) & 1u)) >> 16;
    return (short)r;
}
__device__ __forceinline__ float bf2f(short s) {
    unsigned u = ((unsigned)(unsigned short)s) << 16;
    return __builtin_bit_cast(float, u);
}
__device__ __forceinline__ float tanh_fast(float x) {
    float e = __expf(2.0f * x);
    return fmaf(-2.0f, __builtin_amdgcn_rcpf(e + 1.0f), 1.0f);
}

// ---------------------------------------------------------------------------
// CSR build
__global__ __launch_bounds__(256) void hist_kernel(const int* __restrict__ dst,
                                                   int* __restrict__ counts, int E) {
    int i = blockIdx.x * blockDim.x + threadIdx.x;
    if (i < E) atomicAdd(&counts[dst[i]], 1);
}

// ---- 3-phase device-wide exclusive scan over counts[n] ----
__global__ __launch_bounds__(256) void blocksum_kernel(const int* __restrict__ counts,
                                                       int* __restrict__ blockSums, int n) {
    __shared__ int wsum[4];
    int i = blockIdx.x * 256 + threadIdx.x;
    int v = (i < n) ? counts[i] : 0;
#pragma unroll
    for (int off = 1; off < 64; off <<= 1) v += __shfl_xor(v, off);
    if ((threadIdx.x & 63) == 0) wsum[threadIdx.x >> 6] = v;
    __syncthreads();
    if (threadIdx.x == 0)
        blockSums[blockIdx.x] = wsum[0] + wsum[1] + wsum[2] + wsum[3];
}

__global__ __launch_bounds__(1024) void blockscan_kernel(int* __restrict__ blockSums, int nb) {
    __shared__ int lds[1024];
    int t = threadIdx.x;
    int v = (t < nb) ? blockSums[t] : 0;
    lds[t] = v;
    __syncthreads();
    for (int off = 1; off < 1024; off <<= 1) {
        int u = (t >= off) ? lds[t - off] : 0;
        __syncthreads();
        lds[t] += u;
        __syncthreads();
    }
    if (t < nb) blockSums[t] = (t == 0) ? 0 : lds[t - 1];   // exclusive
}

__global__ __launch_bounds__(256) void scanout_kernel(const int* __restrict__ counts,
                                                      const int* __restrict__ blockSums,
                                                      int* __restrict__ offsets,
                                                      int* __restrict__ cursor, int n) {
    __shared__ int wsum[4];
    int t = threadIdx.x;
    int i = blockIdx.x * 256 + t;
    int lane = t & 63;
    int w = t >> 6;
    int v = (i < n) ? counts[i] : 0;
    int incl = v;
#pragma unroll
    for (int off = 1; off < 64; off <<= 1) {
        int u = __shfl_up(incl, off);
        if (lane >= off) incl += u;
    }
    if (lane == 63) wsum[w] = incl;
    __syncthreads();
    int woff = 0;
#pragma unroll
    for (int j = 0; j < 4; ++j) if (j < w) woff += wsum[j];
    int excl = incl - v + woff + blockSums[blockIdx.x];
    if (i < n) { offsets[i] = excl; cursor[i] = excl; }
    if (i == n - 1) offsets[n] = excl + v;
}

// scatter src/etype into CSR order (removes eids indirection in agg)
__global__ __launch_bounds__(256) void scatter_kernel(const int* __restrict__ dst,
                                                      const int* __restrict__ src,
                                                      const int* __restrict__ etype,
                                                      int* __restrict__ cursor,
                                                      int* __restrict__ srcs,
                                                      int* __restrict__ etys, int E) {
    int i = blockIdx.x * blockDim.x + threadIdx.x;
    if (i < E) {
        int pos = atomicAdd(&cursor[dst[i]], 1);
        srcs[pos] = src[i];
        etys[pos] = etype[i];
    }
}

// ---------------------------------------------------------------------------
__global__ __launch_bounds__(256) void entcvt_kernel(const float* __restrict__ ent,
                                                     short* __restrict__ entbf, int tot) {
    int i = blockIdx.x * 256 + threadIdx.x;
    if (i < tot) entbf[i] = f2bf(ent[i]);
}

__global__ __launch_bounds__(256) void wcvt_kernel(const float* __restrict__ WR,
                                                   short* __restrict__ Wbf,
                                                   short* __restrict__ WTbf) {
    int i = blockIdx.x * 256 + threadIdx.x;     // 65536 threads
    int r = i >> 12, k = (i >> 6) & 63, j = i & 63;
    short b = f2bf(WR[i]);
    Wbf[i] = b;
    WTbf[(r << 12) + (j << 6) + k] = b;
}

// ---------------------------------------------------------------------------
// MFMA projq: per wave: 32-node tile, loop over 4 relations (A reused).
// Qbf[node][r][k] = (tanh(ent W_r + rel_r) W_r^T)[node][k]  in bf16
__global__ __launch_bounds__(256) void projq_kernel(const short* __restrict__ entbf,
                                                    const float* __restrict__ rel,
                                                    const short* __restrict__ Wbf,
                                                    const short* __restrict__ WTbf,
                                                    short* __restrict__ Qbf, int N) {
    __shared__ short Tl[4 * 2048];   // per-wave swizzled tanh tile (4KB)
    __shared__ short Tq[4 * 2048];   // per-wave Q repack tile (4KB)
    int lane = threadIdx.x & 63;
    int wid = threadIdx.x >> 6;
    int m0 = (blockIdx.x * 4 + wid) * 32;
    if (m0 >= N) return;             // wave-uniform exit
    int hi = lane >> 5;
    int lo = lane & 31;

    int arow = m0 + lo;
    if (arow >= N) arow = N - 1;
    const short* ap = entbf + ((size_t)arow << 6) + hi * 8;
    bf16x8 A[4];
#pragma unroll
    for (int kk = 0; kk < 4; ++kk) A[kk] = *(const bf16x8*)(ap + kk * 16);

    short* tb = Tl + wid * 2048;
    short* tq = Tq + wid * 2048;

    for (int rr = 0; rr < 4; ++rr) {
        int r = blockIdx.y * 4 + rr;
        const short* wtb = WTbf + ((size_t)r << 12);
        const short* wb  = Wbf  + ((size_t)r << 12);

        // GEMM1: P = ent @ W_r
        f32x16 acc0 = {}, acc1 = {};
#pragma unroll
        for (int kk = 0; kk < 4; ++kk) {
            bf16x8 b0 = *(const bf16x8*)(wtb + lo * DE + kk * 16 + hi * 8);
            bf16x8 b1 = *(const bf16x8*)(wtb + (lo + 32) * DE + kk * 16 + hi * 8);
            acc0 = __builtin_amdgcn_mfma_f32_32x32x16_bf16(A[kk], b0, acc0, 0, 0, 0);
            acc1 = __builtin_amdgcn_mfma_f32_32x32x16_bf16(A[kk], b1, acc1, 0, 0, 0);
        }
        // tanh(P + rel) -> bf16 -> swizzled LDS (C-layout -> A-layout)
        float rv0 = rel[r * DE + lo];
        float rv1 = rel[r * DE + 32 + lo];
#pragma unroll
        for (int i = 0; i < 16; ++i) {
            int row = (i & 3) + 8 * (i >> 2) + 4 * hi;
            int sw = (row & 7) << 3;
            tb[(row * DE + lo) ^ sw] = f2bf(tanh_fast(acc0[i] + rv0));
            tb[(row * DE + 32 + lo) ^ sw] = f2bf(tanh_fast(acc1[i] + rv1));
        }
        bf16x8 A2[4];
#pragma unroll
        for (int kk = 0; kk < 4; ++kk)
            A2[kk] = *(const bf16x8*)(tb + ((lo * DE + kk * 16 + hi * 8) ^ ((lo & 7) << 3)));

        // GEMM2: Qt = T @ W_r^T
        f32x16 q0 = {}, q1 = {};
#pragma unroll
        for (int kk = 0; kk < 4; ++kk) {
            bf16x8 b0 = *(const bf16x8*)(wb + lo * DE + kk * 16 + hi * 8);
            bf16x8 b1 = *(const bf16x8*)(wb + (lo + 32) * DE + kk * 16 + hi * 8);
            q0 = __builtin_amdgcn_mfma_f32_32x32x16_bf16(A2[kk], b0, q0, 0, 0, 0);
            q1 = __builtin_amdgcn_mfma_f32_32x32x16_bf16(A2[kk], b1, q1, 0, 0, 0);
        }
        // repack to row-major bf16 in LDS, then 16B coalesced stores
#pragma unroll
        for (int i = 0; i < 16; ++i) {
            int row = (i & 3) + 8 * (i >> 2) + 4 * hi;
            tq[row * DE + lo] = f2bf(q0[i]);
            tq[row * DE + 32 + lo] = f2bf(q1[i]);
        }
#pragma unroll
        for (int p = 0; p < 4; ++p) {
            int row = p * 8 + (lane >> 3);
            int node = m0 + row;
            bf16x8 vq = *(const bf16x8*)(tq + row * DE + (lane & 7) * 8);
            if (node < N)
                *(bf16x8*)(Qbf + (((size_t)node * NREL + r) << 6) + (lane & 7) * 8) = vq;
        }
    }
}

// ---------------------------------------------------------------------------
// Fused agg: one wave per dst node; 8 edges in flight (8 lanes each),
// depth-1 prefetch, per-group online softmax, 3-step merge, LDS-broadcast MLP.
__global__ __launch_bounds__(256) void agg_kernel(const float* __restrict__ ent,
                                                  const short* __restrict__ entbf,
                                                  const short* __restrict__ Qbf,
                                                  const int* __restrict__ offsets,
                                                  const int* __restrict__ srcs,
                                                  const int* __restrict__ etys,
                                                  const float* __restrict__ W1,
                                                  const float* __restrict__ b1,
                                                  const float* __restrict__ W2,
                                                  const float* __restrict__ b2,
                                                  float* __restrict__ out, int n) {
    __shared__ float xl[4][128];
    int lane = threadIdx.x & 63;
    int wid = threadIdx.x >> 6;
    int v = (blockIdx.x << 2) + wid;
    if (v >= n) return;
    int o0 = offsets[v], o1 = offsets[v + 1];
    int g = lane >> 3, gl = lane & 7;
    const short* qbase = Qbf + ((size_t)v << 10) + gl * 8;

    float m = -INFINITY, l = 0.f;
    float acc[8];
#pragma unroll
    for (int j = 0; j < 8; ++j) acc[j] = 0.f;

    int k = o0 + g;
    bool val = k < o1;
    bf16x8 xv = {}, qv = {};
    if (val) {
        int s = srcs[k];
        int r = etys[k];
        xv = *(const bf16x8*)(entbf + ((size_t)s << 6) + gl * 8);
        qv = *(const bf16x8*)(qbase + (r << 6));
    }
    int iters = (o1 - o0 + 7) >> 3;
    for (int it = 0; it < iters; ++it) {
        // prefetch next group-of-8
        int kn = k + 8;
        bool valn = kn < o1;
        bf16x8 xn = {}, qn = {};
        if (valn) {
            int s = srcs[kn];
            int r = etys[kn];
            xn = *(const bf16x8*)(entbf + ((size_t)s << 6) + gl * 8);
            qn = *(const bf16x8*)(qbase + (r << 6));
        }
        // att dot over 8 lanes
        float xf[8];
        float d = 0.f;
#pragma unroll
        for (int j = 0; j < 8; ++j) {
            xf[j] = bf2f(xv[j]);
            d = fmaf(xf[j], bf2f(qv[j]), d);
        }
        d += __shfl_xor(d, 1);
        d += __shfl_xor(d, 2);
        d += __shfl_xor(d, 4);
        float p = val ? d : -INFINITY;
        // online softmax update (per group)
        float nm = fmaxf(m, p);
        float sc, pe;
        if (nm == -INFINITY) { sc = 0.f; pe = 0.f; }
        else { sc = __expf(m - nm); pe = __expf(p - nm); }
        l = l * sc + pe;
#pragma unroll
        for (int j = 0; j < 8; ++j) acc[j] = fmaf(acc[j], sc, pe * xf[j]);
        m = nm;
        k = kn; val = valn; xv = xn; qv = qn;
    }
    // merge the 8 group-partials (group id = lane bits 3..5)
#pragma unroll
    for (int off = 8; off < 64; off <<= 1) {
        float mo = __shfl_xor(m, off);
        float lo2 = __shfl_xor(l, off);
        float nm = fmaxf(m, mo);
        float s1 = (nm == -INFINITY) ? 0.f : __expf(m - nm);
        float s2 = (nm == -INFINITY) ? 0.f : __expf(mo - nm);
        l = l * s1 + lo2 * s2;
#pragma unroll
        for (int j = 0; j < 8; ++j) {
            float ao = __shfl_xor(acc[j], off);
            acc[j] = acc[j] * s1 + ao * s2;
        }
        m = nm;
    }
    // redistribute Nh (feats gl*8..+7 per lane) -> lane=feat via LDS
    float* xw = &xl[wid][0];
    float invl = (l > 0.f) ? (1.0f / l) : 0.f;
    if (g == 0) {
#pragma unroll
        for (int j = 0; j < 8; ++j) xw[gl * 8 + j] = acc[j] * invl;
    }
    float node = ent[((size_t)v << 6) + lane];
    float Nh = xw[lane];                 // same-wave LDS RAW (compiler waits)
    float x1 = node + Nh;
    float x2 = node * Nh;
    xw[lane] = x1;
    xw[64 + lane] = x2;
    int j = lane & 31;
    const float* __restrict__ Wsel = (lane < 32) ? W1 : W2;
    float bias = (lane < 32) ? b1[j] : b2[j];
    const float* xb = xw + ((lane < 32) ? 0 : 64);
    float o = 0.f;
#pragma unroll 8
    for (int kk = 0; kk < DE; ++kk)
        o = fmaf(xb[kk], Wsel[kk * DOUT + j], o);
    o += bias;
    float lr = (o > 0.f) ? o : 0.01f * o;
    float other = __shfl_xor(lr, 32);
    if (lane < 32) out[(size_t)v * DOUT + lane] = lr + other;
}

// ---------------------------------------------------------------------------
extern "C" void kernel_launch(void* const* d_in, const int* in_sizes, int n_in,
                              void* d_out, int out_size, void* d_ws, size_t ws_size,
                              hipStream_t stream) {
    const float* ent = (const float*)d_in[0];
    const float* rel = (const float*)d_in[1];
    const float* WR  = (const float*)d_in[2];
    const float* W1  = (const float*)d_in[3];
    const float* b1  = (const float*)d_in[4];
    const float* W2  = (const float*)d_in[5];
    const float* b2  = (const float*)d_in[6];
    const int* src   = (const int*)d_in[7];
    const int* dst   = (const int*)d_in[8];
    const int* ety   = (const int*)d_in[9];
    float* out       = (float*)d_out;

    const int E = in_sizes[7];
    const int N = in_sizes[0] / DE;
    const int NB = (N + 255) / 256;             // 196 partial blocks (<=1024)

    size_t qElems  = (size_t)N * NREL * DE;     // 51.2M bf16 = 102.4 MB
    size_t eElems  = (size_t)N * DE;            // 3.2M bf16
    size_t wElems  = (size_t)NREL * DE * DE;    // 65536 bf16

    char* ws = (char*)d_ws;
    short* Qbf   = (short*)ws;
    short* entbf = Qbf + qElems;
    short* Wbf   = entbf + eElems;
    short* WTbf  = Wbf + wElems;
    int* counts  = (int*)(WTbf + wElems);
    int* offsets = counts + N;
    int* cursor  = offsets + N + 1;
    int* srcs    = cursor + N;
    int* etys    = srcs + E;
    int* bsums   = etys + E;                    // NB ints
    size_t need  = (size_t)((char*)(bsums + NB) - ws);
    if (ws_size < need) return;                 // ~118 MB needed, ~213 MB available

    hipMemsetAsync(counts, 0, (size_t)N * 4, stream);
    entcvt_kernel<<<(int)((eElems + 255) / 256), 256, 0, stream>>>(ent, entbf, (int)eElems);
    wcvt_kernel<<<(int)(wElems / 256), 256, 0, stream>>>(WR, Wbf, WTbf);
    hist_kernel<<<(E + 255) / 256, 256, 0, stream>>>(dst, counts, E);
    blocksum_kernel<<<NB, 256, 0, stream>>>(counts, bsums, N);
    blockscan_kernel<<<1, 1024, 0, stream>>>(bsums, NB);
    scanout_kernel<<<NB, 256, 0, stream>>>(counts, bsums, offsets, cursor, N);
    scatter_kernel<<<(E + 255) / 256, 256, 0, stream>>>(dst, src, ety, cursor, srcs, etys, E);
    projq_kernel<<<dim3((N + 127) / 128, 4), 256, 0, stream>>>(entbf, rel, Wbf, WTbf, Qbf, N);
    agg_kernel<<<(N + 3) / 4, 256, 0, stream>>>(ent, entbf, Qbf, offsets, srcs, etys,
                                                W1, b1, W2, b2, out, N);
}

// Round 6
// 254.175 us; speedup vs baseline: 6.8205x; 1.0552x over previous
//
#include <hip/hip_runtime.h>
#include <math.h>

#define NREL 16
#define DE 64
#define DOUT 32

typedef __attribute__((ext_vector_type(8))) short bf16x8;
typedef __attribute__((ext_vector_type(16))) float f32x16;

__device__ __forceinline__ short f2bf(float f) {
    unsigned u = __builtin_bit_cast(unsigned, f);
    unsigned r = (u + 0x7FFFu + ((u >> 16) & 1u)) >> 16;
    return (short)r;
}
__device__ __forceinline__ float bf2f(short s) {
    unsigned u = ((unsigned)(unsigned short)s) << 16;
    return __builtin_bit_cast(float, u);
}
__device__ __forceinline__ float tanh_fast(float x) {
    float e = __expf(2.0f * x);
    return fmaf(-2.0f, __builtin_amdgcn_rcpf(e + 1.0f), 1.0f);
}

// ---------------------------------------------------------------------------
// CSR build
__global__ __launch_bounds__(256) void hist_kernel(const int* __restrict__ dst,
                                                   int* __restrict__ counts, int E) {
    int i = blockIdx.x * blockDim.x + threadIdx.x;
    if (i < E) atomicAdd(&counts[dst[i]], 1);
}

// ---- 3-phase device-wide exclusive scan over counts[n] ----
__global__ __launch_bounds__(256) void blocksum_kernel(const int* __restrict__ counts,
                                                       int* __restrict__ blockSums, int n) {
    __shared__ int wsum[4];
    int i = blockIdx.x * 256 + threadIdx.x;
    int v = (i < n) ? counts[i] : 0;
#pragma unroll
    for (int off = 1; off < 64; off <<= 1) v += __shfl_xor(v, off);
    if ((threadIdx.x & 63) == 0) wsum[threadIdx.x >> 6] = v;
    __syncthreads();
    if (threadIdx.x == 0)
        blockSums[blockIdx.x] = wsum[0] + wsum[1] + wsum[2] + wsum[3];
}

__global__ __launch_bounds__(1024) void blockscan_kernel(int* __restrict__ blockSums, int nb) {
    __shared__ int lds[1024];
    int t = threadIdx.x;
    int v = (t < nb) ? blockSums[t] : 0;
    lds[t] = v;
    __syncthreads();
    for (int off = 1; off < 1024; off <<= 1) {
        int u = (t >= off) ? lds[t - off] : 0;
        __syncthreads();
        lds[t] += u;
        __syncthreads();
    }
    if (t < nb) blockSums[t] = (t == 0) ? 0 : lds[t - 1];   // exclusive
}

__global__ __launch_bounds__(256) void scanout_kernel(const int* __restrict__ counts,
                                                      const int* __restrict__ blockSums,
                                                      int* __restrict__ offsets,
                                                      int* __restrict__ cursor, int n) {
    __shared__ int wsum[4];
    int t = threadIdx.x;
    int i = blockIdx.x * 256 + t;
    int lane = t & 63;
    int w = t >> 6;
    int v = (i < n) ? counts[i] : 0;
    int incl = v;
#pragma unroll
    for (int off = 1; off < 64; off <<= 1) {
        int u = __shfl_up(incl, off);
        if (lane >= off) incl += u;
    }
    if (lane == 63) wsum[w] = incl;
    __syncthreads();
    int woff = 0;
#pragma unroll
    for (int j = 0; j < 4; ++j) if (j < w) woff += wsum[j];
    int excl = incl - v + woff + blockSums[blockIdx.x];
    if (i < n) { offsets[i] = excl; cursor[i] = excl; }
    if (i == n - 1) offsets[n] = excl + v;
}

// scatter packed (src<<4 | ety) into CSR order — ONE 4B store per edge
__global__ __launch_bounds__(256) void scatter_kernel(const int* __restrict__ dst,
                                                      const int* __restrict__ src,
                                                      const int* __restrict__ etype,
                                                      int* __restrict__ cursor,
                                                      int* __restrict__ pks, int E) {
    int i = blockIdx.x * blockDim.x + threadIdx.x;
    if (i < E) {
        int pos = atomicAdd(&cursor[dst[i]], 1);
        pks[pos] = (src[i] << 4) | etype[i];
    }
}

// ---------------------------------------------------------------------------
__global__ __launch_bounds__(256) void entcvt_kernel(const float* __restrict__ ent,
                                                     short* __restrict__ entbf, int tot) {
    int i = blockIdx.x * 256 + threadIdx.x;
    if (i < tot) entbf[i] = f2bf(ent[i]);
}

__global__ __launch_bounds__(256) void wcvt_kernel(const float* __restrict__ WR,
                                                   short* __restrict__ Wbf,
                                                   short* __restrict__ WTbf) {
    int i = blockIdx.x * 256 + threadIdx.x;     // 65536 threads
    int r = i >> 12, k = (i >> 6) & 63, j = i & 63;
    short b = f2bf(WR[i]);
    Wbf[i] = b;
    WTbf[(r << 12) + (j << 6) + k] = b;
}

// ---------------------------------------------------------------------------
// MFMA projq: per wave: 32-node tile, loop over 4 relations (A reused).
// Qbf[node][r][k] = (tanh(ent W_r + rel_r) W_r^T)[node][k]  in bf16
__global__ __launch_bounds__(256) void projq_kernel(const short* __restrict__ entbf,
                                                    const float* __restrict__ rel,
                                                    const short* __restrict__ Wbf,
                                                    const short* __restrict__ WTbf,
                                                    short* __restrict__ Qbf, int N) {
    __shared__ short Tl[4 * 2048];   // per-wave swizzled tanh tile (4KB)
    __shared__ short Tq[4 * 2048];   // per-wave Q repack tile (4KB)
    int lane = threadIdx.x & 63;
    int wid = threadIdx.x >> 6;
    int m0 = (blockIdx.x * 4 + wid) * 32;
    if (m0 >= N) return;             // wave-uniform exit
    int hi = lane >> 5;
    int lo = lane & 31;

    int arow = m0 + lo;
    if (arow >= N) arow = N - 1;
    const short* ap = entbf + ((size_t)arow << 6) + hi * 8;
    bf16x8 A[4];
#pragma unroll
    for (int kk = 0; kk < 4; ++kk) A[kk] = *(const bf16x8*)(ap + kk * 16);

    short* tb = Tl + wid * 2048;
    short* tq = Tq + wid * 2048;

    for (int rr = 0; rr < 4; ++rr) {
        int r = blockIdx.y * 4 + rr;
        const short* wtb = WTbf + ((size_t)r << 12);
        const short* wb  = Wbf  + ((size_t)r << 12);

        // GEMM1: P = ent @ W_r
        f32x16 acc0 = {}, acc1 = {};
#pragma unroll
        for (int kk = 0; kk < 4; ++kk) {
            bf16x8 b0 = *(const bf16x8*)(wtb + lo * DE + kk * 16 + hi * 8);
            bf16x8 b1 = *(const bf16x8*)(wtb + (lo + 32) * DE + kk * 16 + hi * 8);
            acc0 = __builtin_amdgcn_mfma_f32_32x32x16_bf16(A[kk], b0, acc0, 0, 0, 0);
            acc1 = __builtin_amdgcn_mfma_f32_32x32x16_bf16(A[kk], b1, acc1, 0, 0, 0);
        }
        // tanh(P + rel) -> bf16 -> swizzled LDS (C-layout -> A-layout)
        float rv0 = rel[r * DE + lo];
        float rv1 = rel[r * DE + 32 + lo];
#pragma unroll
        for (int i = 0; i < 16; ++i) {
            int row = (i & 3) + 8 * (i >> 2) + 4 * hi;
            int sw = (row & 7) << 3;
            tb[(row * DE + lo) ^ sw] = f2bf(tanh_fast(acc0[i] + rv0));
            tb[(row * DE + 32 + lo) ^ sw] = f2bf(tanh_fast(acc1[i] + rv1));
        }
        bf16x8 A2[4];
#pragma unroll
        for (int kk = 0; kk < 4; ++kk)
            A2[kk] = *(const bf16x8*)(tb + ((lo * DE + kk * 16 + hi * 8) ^ ((lo & 7) << 3)));

        // GEMM2: Qt = T @ W_r^T
        f32x16 q0 = {}, q1 = {};
#pragma unroll
        for (int kk = 0; kk < 4; ++kk) {
            bf16x8 b0 = *(const bf16x8*)(wb + lo * DE + kk * 16 + hi * 8);
            bf16x8 b1 = *(const bf16x8*)(wb + (lo + 32) * DE + kk * 16 + hi * 8);
            q0 = __builtin_amdgcn_mfma_f32_32x32x16_bf16(A2[kk], b0, q0, 0, 0, 0);
            q1 = __builtin_amdgcn_mfma_f32_32x32x16_bf16(A2[kk], b1, q1, 0, 0, 0);
        }
        // repack to row-major bf16 in LDS, then 16B coalesced stores
#pragma unroll
        for (int i = 0; i < 16; ++i) {
            int row = (i & 3) + 8 * (i >> 2) + 4 * hi;
            tq[row * DE + lo] = f2bf(q0[i]);
            tq[row * DE + 32 + lo] = f2bf(q1[i]);
        }
#pragma unroll
        for (int p = 0; p < 4; ++p) {
            int row = p * 8 + (lane >> 3);
            int node = m0 + row;
            bf16x8 vq = *(const bf16x8*)(tq + row * DE + (lane & 7) * 8);
            if (node < N)
                *(bf16x8*)(Qbf + (((size_t)node * NREL + r) << 6) + (lane & 7) * 8) = vq;
        }
    }
}

// ---------------------------------------------------------------------------
// Fused agg: one wave per dst node; 8 edges in flight (8 lanes each),
// depth-1 prefetch, per-group online softmax, 3-step merge, LDS-broadcast MLP.
__global__ __launch_bounds__(256) void agg_kernel(const float* __restrict__ ent,
                                                  const short* __restrict__ entbf,
                                                  const short* __restrict__ Qbf,
                                                  const int* __restrict__ offsets,
                                                  const int* __restrict__ pks,
                                                  const float* __restrict__ W1,
                                                  const float* __restrict__ b1,
                                                  const float* __restrict__ W2,
                                                  const float* __restrict__ b2,
                                                  float* __restrict__ out, int n) {
    __shared__ float xl[4][128];
    int lane = threadIdx.x & 63;
    int wid = threadIdx.x >> 6;
    int v = (blockIdx.x << 2) + wid;
    if (v >= n) return;
    int o0 = offsets[v], o1 = offsets[v + 1];
    int g = lane >> 3, gl = lane & 7;
    const short* qbase = Qbf + ((size_t)v << 10) + gl * 8;

    float m = -INFINITY, l = 0.f;
    float acc[8];
#pragma unroll
    for (int j = 0; j < 8; ++j) acc[j] = 0.f;

    int k = o0 + g;
    bool val = k < o1;
    bf16x8 xv = {}, qv = {};
    if (val) {
        int pk = pks[k];
        xv = *(const bf16x8*)(entbf + ((size_t)(pk >> 4) << 6) + gl * 8);
        qv = *(const bf16x8*)(qbase + ((pk & 15) << 6));
    }
    int iters = (o1 - o0 + 7) >> 3;
    for (int it = 0; it < iters; ++it) {
        // prefetch next group-of-8
        int kn = k + 8;
        bool valn = kn < o1;
        bf16x8 xn = {}, qn = {};
        if (valn) {
            int pk = pks[kn];
            xn = *(const bf16x8*)(entbf + ((size_t)(pk >> 4) << 6) + gl * 8);
            qn = *(const bf16x8*)(qbase + ((pk & 15) << 6));
        }
        // att dot over 8 lanes
        float xf[8];
        float d = 0.f;
#pragma unroll
        for (int j = 0; j < 8; ++j) {
            xf[j] = bf2f(xv[j]);
            d = fmaf(xf[j], bf2f(qv[j]), d);
        }
        d += __shfl_xor(d, 1);
        d += __shfl_xor(d, 2);
        d += __shfl_xor(d, 4);
        float p = val ? d : -INFINITY;
        // online softmax update (per group)
        float nm = fmaxf(m, p);
        float sc, pe;
        if (nm == -INFINITY) { sc = 0.f; pe = 0.f; }
        else { sc = __expf(m - nm); pe = __expf(p - nm); }
        l = l * sc + pe;
#pragma unroll
        for (int j = 0; j < 8; ++j) acc[j] = fmaf(acc[j], sc, pe * xf[j]);
        m = nm;
        k = kn; val = valn; xv = xn; qv = qn;
    }
    // merge the 8 group-partials (group id = lane bits 3..5)
#pragma unroll
    for (int off = 8; off < 64; off <<= 1) {
        float mo = __shfl_xor(m, off);
        float lo2 = __shfl_xor(l, off);
        float nm = fmaxf(m, mo);
        float s1 = (nm == -INFINITY) ? 0.f : __expf(m - nm);
        float s2 = (nm == -INFINITY) ? 0.f : __expf(mo - nm);
        l = l * s1 + lo2 * s2;
#pragma unroll
        for (int j = 0; j < 8; ++j) {
            float ao = __shfl_xor(acc[j], off);
            acc[j] = acc[j] * s1 + ao * s2;
        }
        m = nm;
    }
    // redistribute Nh (feats gl*8..+7 per lane) -> lane=feat via LDS
    float* xw = &xl[wid][0];
    float invl = (l > 0.f) ? (1.0f / l) : 0.f;
    if (g == 0) {
#pragma unroll
        for (int j = 0; j < 8; ++j) xw[gl * 8 + j] = acc[j] * invl;
    }
    float node = ent[((size_t)v << 6) + lane];
    float Nh = xw[lane];                 // same-wave LDS RAW (compiler waits)
    float x1 = node + Nh;
    float x2 = node * Nh;
    xw[lane] = x1;
    xw[64 + lane] = x2;
    int j = lane & 31;
    const float* __restrict__ Wsel = (lane < 32) ? W1 : W2;
    float bias = (lane < 32) ? b1[j] : b2[j];
    const float* xb = xw + ((lane < 32) ? 0 : 64);
    float o = 0.f;
#pragma unroll 8
    for (int kk = 0; kk < DE; ++kk)
        o = fmaf(xb[kk], Wsel[kk * DOUT + j], o);
    o += bias;
    float lr = (o > 0.f) ? o : 0.01f * o;
    float other = __shfl_xor(lr, 32);
    if (lane < 32) out[(size_t)v * DOUT + lane] = lr + other;
}

// ---------------------------------------------------------------------------
extern "C" void kernel_launch(void* const* d_in, const int* in_sizes, int n_in,
                              void* d_out, int out_size, void* d_ws, size_t ws_size,
                              hipStream_t stream) {
    const float* ent = (const float*)d_in[0];
    const float* rel = (const float*)d_in[1];
    const float* WR  = (const float*)d_in[2];
    const float* W1  = (const float*)d_in[3];
    const float* b1  = (const float*)d_in[4];
    const float* W2  = (const float*)d_in[5];
    const float* b2  = (const float*)d_in[6];
    const int* src   = (const int*)d_in[7];
    const int* dst   = (const int*)d_in[8];
    const int* ety   = (const int*)d_in[9];
    float* out       = (float*)d_out;

    const int E = in_sizes[7];
    const int N = in_sizes[0] / DE;
    const int NB = (N + 255) / 256;             // 196 partial blocks (<=1024)

    size_t qElems  = (size_t)N * NREL * DE;     // 51.2M bf16 = 102.4 MB
    size_t eElems  = (size_t)N * DE;            // 3.2M bf16
    size_t wElems  = (size_t)NREL * DE * DE;    // 65536 bf16

    char* ws = (char*)d_ws;
    short* Qbf   = (short*)ws;
    short* entbf = Qbf + qElems;
    short* Wbf   = entbf + eElems;
    short* WTbf  = Wbf + wElems;
    int* counts  = (int*)(WTbf + wElems);
    int* offsets = counts + N;
    int* cursor  = offsets + N + 1;
    int* pks     = cursor + N;                  // E packed (src<<4|ety)
    int* bsums   = pks + E;                     // NB ints
    size_t need  = (size_t)((char*)(bsums + NB) - ws);
    if (ws_size < need) return;                 // ~114 MB needed, ~213 MB available

    hipMemsetAsync(counts, 0, (size_t)N * 4, stream);
    entcvt_kernel<<<(int)((eElems + 255) / 256), 256, 0, stream>>>(ent, entbf, (int)eElems);
    wcvt_kernel<<<(int)(wElems / 256), 256, 0, stream>>>(WR, Wbf, WTbf);
    hist_kernel<<<(E + 255) / 256, 256, 0, stream>>>(dst, counts, E);
    blocksum_kernel<<<NB, 256, 0, stream>>>(counts, bsums, N);
    blockscan_kernel<<<1, 1024, 0, stream>>>(bsums, NB);
    scanout_kernel<<<NB, 256, 0, stream>>>(counts, bsums, offsets, cursor, N);
    scatter_kernel<<<(E + 255) / 256, 256, 0, stream>>>(dst, src, ety, cursor, pks, E);
    projq_kernel<<<dim3((N + 127) / 128, 4), 256, 0, stream>>>(entbf, rel, Wbf, WTbf, Qbf, N);
    agg_kernel<<<(N + 3) / 4, 256, 0, stream>>>(ent, entbf, Qbf, offsets, pks,
                                                W1, b1, W2, b2, out, N);
}

// Round 7
// 249.271 us; speedup vs baseline: 6.9547x; 1.0197x over previous
//
#include <hip/hip_runtime.h>
#include <math.h>

#define NREL 16
#define DE 64
#define DOUT 32

typedef __attribute__((ext_vector_type(8))) short bf16x8;
typedef __attribute__((ext_vector_type(16))) float f32x16;

__device__ __forceinline__ short f2bf(float f) {
    unsigned u = __builtin_bit_cast(unsigned, f);
    unsigned r = (u + 0x7FFFu + ((u >> 16) & 1u)) >> 16;
    return (short)r;
}
__device__ __forceinline__ float bf2f(short s) {
    unsigned u = ((unsigned)(unsigned short)s) << 16;
    return __builtin_bit_cast(float, u);
}
// packed f32x2 -> bf16x2 (1 instr; no builtin on gfx950)
__device__ __forceinline__ unsigned cvt_pk_bf16(float lo, float hi) {
    unsigned r;
    asm("v_cvt_pk_bf16_f32 %0, %1, %2" : "=v"(r) : "v"(lo), "v"(hi));
    return r;
}
__device__ __forceinline__ float tanh_fast(float x) {
    float e = __expf(2.0f * x);
    return fmaf(-2.0f, __builtin_amdgcn_rcpf(e + 1.0f), 1.0f);
}

// ---------------------------------------------------------------------------
// CSR build
__global__ __launch_bounds__(256) void hist_kernel(const int* __restrict__ dst,
                                                   int* __restrict__ counts, int E) {
    int i = blockIdx.x * blockDim.x + threadIdx.x;
    if (i < E) atomicAdd(&counts[dst[i]], 1);
}

// ---- 3-phase device-wide exclusive scan over counts[n] ----
__global__ __launch_bounds__(256) void blocksum_kernel(const int* __restrict__ counts,
                                                       int* __restrict__ blockSums, int n) {
    __shared__ int wsum[4];
    int i = blockIdx.x * 256 + threadIdx.x;
    int v = (i < n) ? counts[i] : 0;
#pragma unroll
    for (int off = 1; off < 64; off <<= 1) v += __shfl_xor(v, off);
    if ((threadIdx.x & 63) == 0) wsum[threadIdx.x >> 6] = v;
    __syncthreads();
    if (threadIdx.x == 0)
        blockSums[blockIdx.x] = wsum[0] + wsum[1] + wsum[2] + wsum[3];
}

__global__ __launch_bounds__(1024) void blockscan_kernel(int* __restrict__ blockSums, int nb) {
    __shared__ int lds[1024];
    int t = threadIdx.x;
    int v = (t < nb) ? blockSums[t] : 0;
    lds[t] = v;
    __syncthreads();
    for (int off = 1; off < 1024; off <<= 1) {
        int u = (t >= off) ? lds[t - off] : 0;
        __syncthreads();
        lds[t] += u;
        __syncthreads();
    }
    if (t < nb) blockSums[t] = (t == 0) ? 0 : lds[t - 1];   // exclusive
}

__global__ __launch_bounds__(256) void scanout_kernel(const int* __restrict__ counts,
                                                      const int* __restrict__ blockSums,
                                                      int* __restrict__ offsets,
                                                      int* __restrict__ cursor, int n) {
    __shared__ int wsum[4];
    int t = threadIdx.x;
    int i = blockIdx.x * 256 + t;
    int lane = t & 63;
    int w = t >> 6;
    int v = (i < n) ? counts[i] : 0;
    int incl = v;
#pragma unroll
    for (int off = 1; off < 64; off <<= 1) {
        int u = __shfl_up(incl, off);
        if (lane >= off) incl += u;
    }
    if (lane == 63) wsum[w] = incl;
    __syncthreads();
    int woff = 0;
#pragma unroll
    for (int j = 0; j < 4; ++j) if (j < w) woff += wsum[j];
    int excl = incl - v + woff + blockSums[blockIdx.x];
    if (i < n) { offsets[i] = excl; cursor[i] = excl; }
    if (i == n - 1) offsets[n] = excl + v;
}

// scatter packed (src<<4 | ety) into CSR order — ONE 4B store per edge
__global__ __launch_bounds__(256) void scatter_kernel(const int* __restrict__ dst,
                                                      const int* __restrict__ src,
                                                      const int* __restrict__ etype,
                                                      int* __restrict__ cursor,
                                                      int* __restrict__ pks, int E) {
    int i = blockIdx.x * blockDim.x + threadIdx.x;
    if (i < E) {
        int pos = atomicAdd(&cursor[dst[i]], 1);
        pks[pos] = (src[i] << 4) | etype[i];
    }
}

// ---------------------------------------------------------------------------
__global__ __launch_bounds__(256) void entcvt_kernel(const float* __restrict__ ent,
                                                     short* __restrict__ entbf, int tot) {
    int i = blockIdx.x * 256 + threadIdx.x;
    if (i < tot) entbf[i] = f2bf(ent[i]);
}

__global__ __launch_bounds__(256) void wcvt_kernel(const float* __restrict__ WR,
                                                   short* __restrict__ Wbf,
                                                   short* __restrict__ WTbf) {
    int i = blockIdx.x * 256 + threadIdx.x;     // 65536 threads
    int r = i >> 12, k = (i >> 6) & 63, j = i & 63;
    short b = f2bf(WR[i]);
    Wbf[i] = b;
    WTbf[(r << 12) + (j << 6) + k] = b;
}

// ---------------------------------------------------------------------------
// MFMA projq: per wave: 32-node tile, loop over 4 relations (A reused).
// Qbf[r][node][k] = (tanh(ent W_r + rel_r) W_r^T)[node][k]  in bf16
__global__ __launch_bounds__(256) void projq_kernel(const short* __restrict__ entbf,
                                                    const float* __restrict__ rel,
                                                    const short* __restrict__ Wbf,
                                                    const short* __restrict__ WTbf,
                                                    short* __restrict__ Qbf, int N) {
    __shared__ short Tl[4 * 2048];   // per-wave swizzled tile (4KB), reused for repack
    int lane = threadIdx.x & 63;
    int wid = threadIdx.x >> 6;
    int m0 = (blockIdx.x * 4 + wid) * 32;
    if (m0 >= N) return;             // wave-uniform exit
    int hi = lane >> 5;
    int lo = lane & 31;

    int arow = m0 + lo;
    if (arow >= N) arow = N - 1;
    const short* ap = entbf + ((size_t)arow << 6) + hi * 8;
    bf16x8 A[4];
#pragma unroll
    for (int kk = 0; kk < 4; ++kk) A[kk] = *(const bf16x8*)(ap + kk * 16);

    short* tb = Tl + wid * 2048;

    for (int rr = 0; rr < 4; ++rr) {
        int r = blockIdx.y * 4 + rr;
        const short* wtb = WTbf + ((size_t)r << 12);
        const short* wb  = Wbf  + ((size_t)r << 12);

        // GEMM1: P = ent @ W_r
        f32x16 acc0 = {}, acc1 = {};
#pragma unroll
        for (int kk = 0; kk < 4; ++kk) {
            bf16x8 b0 = *(const bf16x8*)(wtb + lo * DE + kk * 16 + hi * 8);
            bf16x8 b1 = *(const bf16x8*)(wtb + (lo + 32) * DE + kk * 16 + hi * 8);
            acc0 = __builtin_amdgcn_mfma_f32_32x32x16_bf16(A[kk], b0, acc0, 0, 0, 0);
            acc1 = __builtin_amdgcn_mfma_f32_32x32x16_bf16(A[kk], b1, acc1, 0, 0, 0);
        }
        // tanh(P + rel) -> packed bf16 cvt -> swizzled LDS (C-layout -> A-layout)
        float rv0 = rel[r * DE + lo];
        float rv1 = rel[r * DE + 32 + lo];
#pragma unroll
        for (int i = 0; i < 16; ++i) {
            int row = (i & 3) + 8 * (i >> 2) + 4 * hi;
            int sw = (row & 7) << 3;
            unsigned u = cvt_pk_bf16(tanh_fast(acc0[i] + rv0), tanh_fast(acc1[i] + rv1));
            tb[(row * DE + lo) ^ sw] = (short)(u & 0xffff);
            tb[(row * DE + 32 + lo) ^ sw] = (short)(u >> 16);
        }
        bf16x8 A2[4];
#pragma unroll
        for (int kk = 0; kk < 4; ++kk)
            A2[kk] = *(const bf16x8*)(tb + ((lo * DE + kk * 16 + hi * 8) ^ ((lo & 7) << 3)));

        // GEMM2: Qt = T @ W_r^T
        f32x16 q0 = {}, q1 = {};
#pragma unroll
        for (int kk = 0; kk < 4; ++kk) {
            bf16x8 b0 = *(const bf16x8*)(wb + lo * DE + kk * 16 + hi * 8);
            bf16x8 b1 = *(const bf16x8*)(wb + (lo + 32) * DE + kk * 16 + hi * 8);
            q0 = __builtin_amdgcn_mfma_f32_32x32x16_bf16(A2[kk], b0, q0, 0, 0, 0);
            q1 = __builtin_amdgcn_mfma_f32_32x32x16_bf16(A2[kk], b1, q1, 0, 0, 0);
        }
        // repack to row-major bf16 reusing tb (per-wave private, DS in-order),
        // then 1KB-contiguous wave stores into Q[r][node][k]
#pragma unroll
        for (int i = 0; i < 16; ++i) {
            int row = (i & 3) + 8 * (i >> 2) + 4 * hi;
            unsigned u = cvt_pk_bf16(q0[i], q1[i]);
            tb[row * DE + lo] = (short)(u & 0xffff);
            tb[row * DE + 32 + lo] = (short)(u >> 16);
        }
#pragma unroll
        for (int p = 0; p < 4; ++p) {
            int row = p * 8 + (lane >> 3);
            int node = m0 + row;
            bf16x8 vq = *(const bf16x8*)(tb + row * DE + (lane & 7) * 8);
            if (node < N)
                *(bf16x8*)(Qbf + (((size_t)r * N + node) << 6) + (lane & 7) * 8) = vq;
        }
    }
}

// ---------------------------------------------------------------------------
// Fused agg: one wave per dst node; 8 edges in flight (8 lanes each),
// depth-1 prefetch, per-group online softmax, 3-step merge, LDS-broadcast MLP.
__global__ __launch_bounds__(256) void agg_kernel(const float* __restrict__ ent,
                                                  const short* __restrict__ entbf,
                                                  const short* __restrict__ Qbf,
                                                  const int* __restrict__ offsets,
                                                  const int* __restrict__ pks,
                                                  const float* __restrict__ W1,
                                                  const float* __restrict__ b1,
                                                  const float* __restrict__ W2,
                                                  const float* __restrict__ b2,
                                                  float* __restrict__ out, int n) {
    __shared__ float xl[4][128];
    int lane = threadIdx.x & 63;
    int wid = threadIdx.x >> 6;
    int v = (blockIdx.x << 2) + wid;
    if (v >= n) return;
    int o0 = offsets[v], o1 = offsets[v + 1];
    int g = lane >> 3, gl = lane & 7;
    const short* qbase = Qbf + ((size_t)v << 6) + gl * 8;   // + (r*n)<<6 per edge

    float m = -INFINITY, l = 0.f;
    float acc[8];
#pragma unroll
    for (int j = 0; j < 8; ++j) acc[j] = 0.f;

    int k = o0 + g;
    bool val = k < o1;
    bf16x8 xv = {}, qv = {};
    if (val) {
        int pk = pks[k];
        xv = *(const bf16x8*)(entbf + ((size_t)(pk >> 4) << 6) + gl * 8);
        qv = *(const bf16x8*)(qbase + (((unsigned)(pk & 15) * (unsigned)n) << 6));
    }
    int iters = (o1 - o0 + 7) >> 3;
    for (int it = 0; it < iters; ++it) {
        // prefetch next group-of-8
        int kn = k + 8;
        bool valn = kn < o1;
        bf16x8 xn = {}, qn = {};
        if (valn) {
            int pk = pks[kn];
            xn = *(const bf16x8*)(entbf + ((size_t)(pk >> 4) << 6) + gl * 8);
            qn = *(const bf16x8*)(qbase + (((unsigned)(pk & 15) * (unsigned)n) << 6));
        }
        // att dot over 8 lanes
        float xf[8];
        float d = 0.f;
#pragma unroll
        for (int j = 0; j < 8; ++j) {
            xf[j] = bf2f(xv[j]);
            d = fmaf(xf[j], bf2f(qv[j]), d);
        }
        d += __shfl_xor(d, 1);
        d += __shfl_xor(d, 2);
        d += __shfl_xor(d, 4);
        float p = val ? d : -INFINITY;
        // online softmax update (per group)
        float nm = fmaxf(m, p);
        float sc, pe;
        if (nm == -INFINITY) { sc = 0.f; pe = 0.f; }
        else { sc = __expf(m - nm); pe = __expf(p - nm); }
        l = l * sc + pe;
#pragma unroll
        for (int j = 0; j < 8; ++j) acc[j] = fmaf(acc[j], sc, pe * xf[j]);
        m = nm;
        k = kn; val = valn; xv = xn; qv = qn;
    }
    // merge the 8 group-partials (group id = lane bits 3..5)
#pragma unroll
    for (int off = 8; off < 64; off <<= 1) {
        float mo = __shfl_xor(m, off);
        float lo2 = __shfl_xor(l, off);
        float nm = fmaxf(m, mo);
        float s1 = (nm == -INFINITY) ? 0.f : __expf(m - nm);
        float s2 = (nm == -INFINITY) ? 0.f : __expf(mo - nm);
        l = l * s1 + lo2 * s2;
#pragma unroll
        for (int j = 0; j < 8; ++j) {
            float ao = __shfl_xor(acc[j], off);
            acc[j] = acc[j] * s1 + ao * s2;
        }
        m = nm;
    }
    // redistribute Nh (feats gl*8..+7 per lane) -> lane=feat via LDS
    float* xw = &xl[wid][0];
    float invl = (l > 0.f) ? (1.0f / l) : 0.f;
    if (g == 0) {
#pragma unroll
        for (int j = 0; j < 8; ++j) xw[gl * 8 + j] = acc[j] * invl;
    }
    float node = ent[((size_t)v << 6) + lane];
    float Nh = xw[lane];                 // same-wave LDS RAW (compiler waits)
    float x1 = node + Nh;
    float x2 = node * Nh;
    xw[lane] = x1;
    xw[64 + lane] = x2;
    int j = lane & 31;
    const float* __restrict__ Wsel = (lane < 32) ? W1 : W2;
    float bias = (lane < 32) ? b1[j] : b2[j];
    const float* xb = xw + ((lane < 32) ? 0 : 64);
    float o = 0.f;
#pragma unroll 8
    for (int kk = 0; kk < DE; ++kk)
        o = fmaf(xb[kk], Wsel[kk * DOUT + j], o);
    o += bias;
    float lr = (o > 0.f) ? o : 0.01f * o;
    float other = __shfl_xor(lr, 32);
    if (lane < 32) out[(size_t)v * DOUT + lane] = lr + other;
}

// ---------------------------------------------------------------------------
extern "C" void kernel_launch(void* const* d_in, const int* in_sizes, int n_in,
                              void* d_out, int out_size, void* d_ws, size_t ws_size,
                              hipStream_t stream) {
    const float* ent = (const float*)d_in[0];
    const float* rel = (const float*)d_in[1];
    const float* WR  = (const float*)d_in[2];
    const float* W1  = (const float*)d_in[3];
    const float* b1  = (const float*)d_in[4];
    const float* W2  = (const float*)d_in[5];
    const float* b2  = (const float*)d_in[6];
    const int* src   = (const int*)d_in[7];
    const int* dst   = (const int*)d_in[8];
    const int* ety   = (const int*)d_in[9];
    float* out       = (float*)d_out;

    const int E = in_sizes[7];
    const int N = in_sizes[0] / DE;
    const int NB = (N + 255) / 256;             // 196 partial blocks (<=1024)

    size_t qElems  = (size_t)N * NREL * DE;     // 51.2M bf16 = 102.4 MB
    size_t eElems  = (size_t)N * DE;            // 3.2M bf16
    size_t wElems  = (size_t)NREL * DE * DE;    // 65536 bf16

    char* ws = (char*)d_ws;
    short* Qbf   = (short*)ws;
    short* entbf = Qbf + qElems;
    short* Wbf   = entbf + eElems;
    short* WTbf  = Wbf + wElems;
    int* counts  = (int*)(WTbf + wElems);
    int* offsets = counts + N;
    int* cursor  = offsets + N + 1;
    int* pks     = cursor + N;                  // E packed (src<<4|ety)
    int* bsums   = pks + E;                     // NB ints
    size_t need  = (size_t)((char*)(bsums + NB) - ws);
    if (ws_size < need) return;                 // ~114 MB needed, ~213 MB available

    hipMemsetAsync(counts, 0, (size_t)N * 4, stream);
    entcvt_kernel<<<(int)((eElems + 255) / 256), 256, 0, stream>>>(ent, entbf, (int)eElems);
    wcvt_kernel<<<(int)(wElems / 256), 256, 0, stream>>>(WR, Wbf, WTbf);
    hist_kernel<<<(E + 255) / 256, 256, 0, stream>>>(dst, counts, E);
    blocksum_kernel<<<NB, 256, 0, stream>>>(counts, bsums, N);
    blockscan_kernel<<<1, 1024, 0, stream>>>(bsums, NB);
    scanout_kernel<<<NB, 256, 0, stream>>>(counts, bsums, offsets, cursor, N);
    scatter_kernel<<<(E + 255) / 256, 256, 0, stream>>>(dst, src, ety, cursor, pks, E);
    projq_kernel<<<dim3((N + 127) / 128, 4), 256, 0, stream>>>(entbf, rel, Wbf, WTbf, Qbf, N);
    agg_kernel<<<(N + 3) / 4, 256, 0, stream>>>(ent, entbf, Qbf, offsets, pks,
                                                W1, b1, W2, b2, out, N);
}